// Round 5
// baseline (1817.336 us; speedup 1.0000x reference)
//
#include <hip/hip_runtime.h>
#include <hip/hip_bf16.h>

// Problem constants (B,S,N,F,H,E) = (4,8,4000,64,128,32000)
#define B_  4
#define S_  8
#define N_  4000
#define F_  64
#define H_  128
#define E_  32000
#define G_  (B_*S_)        // 32 graphs
#define GN_ (G_*N_)        // 128000 node rows
#define M_  (B_*N_)        // 16000 LSTM rows
#define GE_ (G_*E_)        // 1,024,000 edges total

// f32 weight scratch offsets (floats)
#define OFF_W0S 0
#define OFF_B0S 8192
#define OFF_W0D 8320
#define OFF_B0D 16512
#define OFF_W1S 16640
#define OFF_B1S 33024
#define OFF_W1D 33152
#define OFF_B1D 49536
#define OFF_WIH 49664
#define OFF_WHH 115200
#define OFF_BIH 180736
#define OFF_BHH 181248
#define OFF_WP  181760
#define OFF_BP  189952
#define WCV_TOTAL 190016

// workspace layout (float offsets)
#define WS_FLAG   0
#define WS_WCV    16
#define WS_WPH    190032      // Whh bf16 packed: 65536 ushorts = 32768 floats
#define WS_DEGO   222800
#define WS_DEGI   350800
#define WS_CNTI   478800
#define WS_CNTO   606800
#define WS_RPI    734800      // 32*4001 = 128032
#define WS_RPO    862832
#define WS_CURI   990864
#define WS_CURO   1118864
#define WS_CSRI   1246864     // int2 x GE = 2,048,000 floats
#define WS_CSRO   3294864
#define WS_P      5342864     // [GN,128] f32 ; gates i,f overwrite as bf16
#define WS_Q      21726864    // [GN,128] f32 ; gates g,o overwrite as bf16
#define WS_HB     38110864    // [GN,128] bf16 = 8,192,000 floats
// total 46,302,864 floats = 185.2 MiB (known-good budget: >=193 MiB)

__device__ inline float bfu2f(unsigned short u){ union{unsigned int i; float f;} v; v.i=((unsigned int)u)<<16; return v.f; }
__device__ inline unsigned short f2bfu(float f){ __hip_bfloat16 b = __float2bfloat16(f); return *(unsigned short*)&b; }
__device__ inline float rcpf(float x){ return __builtin_amdgcn_rcpf(x); }
__device__ inline float sigmf(float x){ return rcpf(1.0f + __expf(-x)); }
__device__ inline float tanhfast(float x){ return 1.0f - 2.0f*rcpf(1.0f + __expf(2.0f*x)); }
__device__ inline float loadf(const void* p, long i, int isf32){
    return isf32 ? ((const float*)p)[i]
                 : __bfloat162float(((const __hip_bfloat16*)p)[i]);
}
__device__ inline void stout(float* p, float v){ *p = v; }
__device__ inline void stout(__hip_bfloat16* p, float v){ *p = __float2bfloat16(v); }
__device__ inline float4 cvtbf4(ushort4 u){
    float4 f;
    f.x = __uint_as_float(((unsigned)u.x)<<16);
    f.y = __uint_as_float(((unsigned)u.y)<<16);
    f.z = __uint_as_float(((unsigned)u.z)<<16);
    f.w = __uint_as_float(((unsigned)u.w)<<16);
    return f;
}

// ---------------- dtype sniff (inputs f32 vs bf16) ----------------
__global__ void sniff_kernel(const unsigned int* __restrict__ ew, int* __restrict__ flag){
    __shared__ int s;
    if (threadIdx.x == 0) s = 0;
    __syncthreads();
    unsigned int lo = ew[threadIdx.x] & 0xFFFFu;
    if (lo > 0x3F80u) atomicOr(&s, 1);
    __syncthreads();
    if (threadIdx.x == 0) flag[0] = s;   // 1 => inputs are f32
}

// ---------------- weight conversion to f32 scratch ----------------
struct WSeg { const void* src; int base; int n; };
struct WDesc { WSeg seg[14]; };
__global__ void convert_weights(WDesc d, float* __restrict__ dst, const int* __restrict__ flag){
    int isf32 = flag[0];
    int idx = blockIdx.x*256 + threadIdx.x;
    #pragma unroll
    for (int s=0;s<14;s++){
        int off = idx - d.seg[s].base;
        if (off >= 0 && off < d.seg[s].n){
            dst[idx] = loadf(d.seg[s].src, off, isf32);
            return;
        }
    }
}

// ---------------- Whh repack: wph[(k*128+j)*4+g] = bf16 Whh[g*128+j][k] ----------------
__global__ void repack_whh(const float* __restrict__ wcv, unsigned short* __restrict__ wph){
    int idx = blockIdx.x*256 + threadIdx.x;   // < 65536
    int g = idx & 3;
    int j = (idx>>2) & 127;
    int k = idx >> 9;
    wph[idx] = f2bfu(wcv[OFF_WHH + (g*128+j)*128 + k]);
}

// ---------------- per-graph histogram: weighted degrees + counts ----------------
__global__ __launch_bounds__(1024) void hist_kernel(
        const int* __restrict__ ei, const void* __restrict__ ew, const int* __restrict__ flag,
        float* __restrict__ deg_o, float* __restrict__ deg_i,
        int* __restrict__ cnt_in, int* __restrict__ cnt_out){
    __shared__ float wdo[N_], wdi[N_];
    __shared__ int   co[N_],  ci[N_];
    int g = blockIdx.x, tid = threadIdx.x;
    int isf32 = flag[0];
    for (int i=tid;i<N_;i+=1024){ wdo[i]=0.f; wdi[i]=0.f; co[i]=0; ci[i]=0; }
    __syncthreads();
    const int* eib = ei + g*2*E_;
    for (int e=tid;e<E_;e+=1024){
        int s = eib[e], d = eib[E_+e];
        float w = loadf(ew, (long)g*E_+e, isf32);
        atomicAdd(&wdo[s], w); atomicAdd(&wdi[d], w);
        atomicAdd(&co[s], 1);  atomicAdd(&ci[d], 1);
    }
    __syncthreads();
    for (int i=tid;i<N_;i+=1024){
        deg_o[g*N_+i]=wdo[i]; deg_i[g*N_+i]=wdi[i];
        cnt_out[g*N_+i]=co[i]; cnt_in[g*N_+i]=ci[i];
    }
}

// ---------------- exclusive scan -> row_ptr + cursors (64 blocks: 32 g x 2 dir) ----------------
__global__ __launch_bounds__(256) void scan_kernel(
        const int* __restrict__ cnt_in, const int* __restrict__ cnt_out,
        int* __restrict__ rp_in, int* __restrict__ rp_out,
        int* __restrict__ cur_in, int* __restrict__ cur_out){
    __shared__ int part[256], pref[256];
    int g = blockIdx.x & 31, dir = blockIdx.x >> 5;
    const int* cnt = (dir ? cnt_out : cnt_in) + g*N_;
    int* rp  = (dir ? rp_out  : rp_in)  + g*(N_+1);
    int* cur = (dir ? cur_out : cur_in) + g*N_;
    int tid = threadIdx.x, base = tid*16;
    int sum = 0;
    for (int i=0;i<16;i++){ int p = base+i; if (p < N_) sum += cnt[p]; }
    part[tid] = sum;
    __syncthreads();
    if (tid == 0){ int run = 0; for (int j=0;j<256;j++){ pref[j] = run; run += part[j]; } }
    __syncthreads();
    int run = pref[tid];
    for (int i=0;i<16;i++){
        int p = base+i;
        if (p < N_){ rp[p] = run; cur[p] = run; run += cnt[p]; }
    }
    if (tid == 255) rp[N_] = run;
}

// ---------------- fill CSR: nrm + scatter edge payloads ----------------
__global__ void fill_kernel(const int* __restrict__ ei, const void* __restrict__ ew,
                            const int* __restrict__ flag,
                            const float* __restrict__ deg_o, const float* __restrict__ deg_i,
                            int* __restrict__ cur_in, int* __restrict__ cur_out,
                            int2* __restrict__ csr_in, int2* __restrict__ csr_out){
    int idx = blockIdx.x*256 + threadIdx.x;
    if (idx >= GE_) return;
    int isf32 = flag[0];
    int g = idx / E_, e = idx - g*E_;
    const int* eib = ei + g*2*E_;
    int s = eib[e], d = eib[E_ + e];
    float dout = deg_o[g*N_+s], din = deg_i[g*N_+d];
    float io = dout > 0.f ? rsqrtf(fmaxf(dout, 1e-12f)) : 0.f;
    float ii = din  > 0.f ? rsqrtf(fmaxf(din , 1e-12f)) : 0.f;
    float nrm = loadf(ew, idx, isf32) * io * ii;
    int p1 = atomicAdd(&cur_in[g*N_+d], 1);
    csr_in[(long)g*E_ + p1] = make_int2(s, __float_as_int(nrm));
    int p2 = atomicAdd(&cur_out[g*N_+s], 1);
    csr_out[(long)g*E_ + p2] = make_int2(d, __float_as_int(nrm));
}

// ---------------- gather layer 0: one wave per (g,dir,node), F=64 ----------------
__global__ void gather64(const int* __restrict__ rp_in, const int* __restrict__ rp_out,
                         const int2* __restrict__ csr_in, const int2* __restrict__ csr_out,
                         const void* __restrict__ x, const int* __restrict__ flag,
                         float* __restrict__ P, float* __restrict__ Q){
    int isf32 = flag[0];
    int wid = blockIdx.x*4 + (threadIdx.x>>6);
    int lane = threadIdx.x & 63;
    int g = wid / (2*N_); int rem = wid - g*(2*N_);
    int dir = rem / N_;   int n = rem - dir*N_;
    const int*  rp  = (dir ? rp_out : rp_in) + g*(N_+1);
    const int2* csr = (dir ? csr_out : csr_in) + (long)g*E_;
    int pb = rp[n], pe = rp[n+1];
    float acc = 0.f;
    for (int p=pb; p<pe; p++){
        int2 ent = csr[p];
        float w = __int_as_float(ent.y);
        acc += w * loadf(x, ((long)(g*N_+ent.x))*64 + lane, isf32);
    }
    float* o = dir ? Q : P;
    o[((long)(g*N_+n))*64 + lane] = acc;
}

// ---------------- gather layer 1: one wave per (g,dir,node), bf16 Hb, F=128 ----------------
__global__ void gather128(const int* __restrict__ rp_in, const int* __restrict__ rp_out,
                          const int2* __restrict__ csr_in, const int2* __restrict__ csr_out,
                          const __hip_bfloat16* __restrict__ hb,
                          float* __restrict__ P, float* __restrict__ Q){
    int wid = blockIdx.x*4 + (threadIdx.x>>6);
    int lane = threadIdx.x & 63;
    int g = wid / (2*N_); int rem = wid - g*(2*N_);
    int dir = rem / N_;   int n = rem - dir*N_;
    const int*  rp  = (dir ? rp_out : rp_in) + g*(N_+1);
    const int2* csr = (dir ? csr_out : csr_in) + (long)g*E_;
    int pb = rp[n], pe = rp[n+1];
    float2 acc = make_float2(0.f, 0.f);
    for (int p=pb; p<pe; p++){
        int2 ent = csr[p];
        float w = __int_as_float(ent.y);
        ushort2 u = ((const ushort2*)(hb + ((long)(g*N_+ent.x))*128))[lane];
        acc.x += w*bfu2f(u.x); acc.y += w*bfu2f(u.y);
    }
    float* o = dir ? Q : P;
    ((float2*)(o + ((long)(g*N_+n))*128))[lane] = acc;
}

// --------- layer-0 GEMM: out(bf16, stride 128) = 0.5*(P@W0s^T+b) + 0.5*(Q@W0d^T+b) ---------
__global__ __launch_bounds__(128) void gemm_dir64(
        const float* __restrict__ Afb, const float* __restrict__ Abb,
        const float* __restrict__ Ws, const float* __restrict__ bs,
        const float* __restrict__ Wd, const float* __restrict__ bd,
        __hip_bfloat16* __restrict__ out){
    __shared__ float4 Af[16][16];
    __shared__ float4 Ab[16][16];
    int j = threadIdx.x;
    int row0 = blockIdx.x * 16;
    const float4* Af_g = (const float4*)(Afb + (size_t)row0*64);
    const float4* Ab_g = (const float4*)(Abb + (size_t)row0*64);
    for (int t = j; t < 16*16; t += 128) {
        ((float4*)Af)[t] = Af_g[t];
        ((float4*)Ab)[t] = Ab_g[t];
    }
    __syncthreads();
    float acc[16];
    #pragma unroll
    for (int r=0;r<16;r++) acc[r]=0.f;
    const float4* Wsv = (const float4*)(Ws + j*64);
    const float4* Wdv = (const float4*)(Wd + j*64);
    for (int k4=0;k4<16;k4++){
        float4 a = Wsv[k4];
        float4 b = Wdv[k4];
        #pragma unroll
        for (int r=0;r<16;r++){
            float4 fa = Af[r][k4];
            float4 fb = Ab[r][k4];
            acc[r] += a.x*fa.x + a.y*fa.y + a.z*fa.z + a.w*fa.w
                    + b.x*fb.x + b.y*fb.y + b.z*fb.z + b.w*fb.w;
        }
    }
    float bias = 0.5f*(bs[j] + bd[j]);
    #pragma unroll
    for (int r=0;r<16;r++) out[(size_t)(row0+r)*128 + j] = __float2bfloat16(0.5f*acc[r] + bias);
}

// ---- fused layer-1 GEMM + LSTM x-gate GEMM ----
// Phase A: h2[16][128] = 0.5*(P@W1s^T+b1s) + 0.5*(Q@W1d^T+b1d)     (in LDS)
// Phase B: gates[16][512] = h2 @ Wih^T + (bih+bhh), stored bf16 IN-PLACE:
//   P row gn (as ushort2[128]): {i,f} at [j];  Q row gn: {g,o} at [j].
__global__ __launch_bounds__(128) void gemm12(
        const float* __restrict__ Pb, const float* __restrict__ Qb,
        const float* __restrict__ wcv,
        float* __restrict__ Pw, float* __restrict__ Qw){
    __shared__ float4 Af[16][32];   // 8 KB; phase B reuses as h2
    __shared__ float4 Ab[16][32];   // 8 KB
    int j = threadIdx.x;
    int row0 = blockIdx.x * 16;
    const float4* Af_g = (const float4*)(Pb + (size_t)row0*128);
    const float4* Ab_g = (const float4*)(Qb + (size_t)row0*128);
    for (int t = j; t < 16*32; t += 128) {
        ((float4*)Af)[t] = Af_g[t];
        ((float4*)Ab)[t] = Ab_g[t];
    }
    __syncthreads();
    float acc[16];
    #pragma unroll
    for (int r=0;r<16;r++) acc[r]=0.f;
    const float4* Wsv = (const float4*)(wcv + OFF_W1S + j*128);
    const float4* Wdv = (const float4*)(wcv + OFF_W1D + j*128);
    for (int k4=0;k4<32;k4++){
        float4 a = Wsv[k4];
        float4 b = Wdv[k4];
        #pragma unroll
        for (int r=0;r<16;r++){
            float4 fa = Af[r][k4];
            float4 fb = Ab[r][k4];
            acc[r] += a.x*fa.x + a.y*fa.y + a.z*fa.z + a.w*fa.w
                    + b.x*fb.x + b.y*fb.y + b.z*fb.z + b.w*fb.w;
        }
    }
    float bias = 0.5f*(wcv[OFF_B1S+j] + wcv[OFF_B1D+j]);
    __syncthreads();          // done reading Af/Ab
    float* h2 = (float*)Af;   // [16][128]
    #pragma unroll
    for (int r=0;r<16;r++) h2[r*128 + j] = 0.5f*acc[r] + bias;
    __syncthreads();
    // Phase B: 4 gate-cols per thread: c = q*128 + j
    float4 accB[16];
    float4 bias4;
    bias4.x = wcv[OFF_BIH+      j] + wcv[OFF_BHH+      j];
    bias4.y = wcv[OFF_BIH+128 + j] + wcv[OFF_BHH+128 + j];
    bias4.z = wcv[OFF_BIH+256 + j] + wcv[OFF_BHH+256 + j];
    bias4.w = wcv[OFF_BIH+384 + j] + wcv[OFF_BHH+384 + j];
    #pragma unroll
    for (int r=0;r<16;r++) accB[r]=bias4;
    const float* wih = wcv + OFF_WIH;
    const float4* wi_v = (const float4*)(wih + (0*128+j)*128);
    const float4* wf_v = (const float4*)(wih + (1*128+j)*128);
    const float4* wg_v = (const float4*)(wih + (2*128+j)*128);
    const float4* wo_v = (const float4*)(wih + (3*128+j)*128);
    for (int k4=0;k4<32;k4++){
        float4 wi = wi_v[k4], wf = wf_v[k4], wg = wg_v[k4], wo = wo_v[k4];
        #pragma unroll
        for (int r=0;r<16;r++){
            float4 hv = *(float4*)(h2 + r*128 + k4*4);
            accB[r].x += wi.x*hv.x + wi.y*hv.y + wi.z*hv.z + wi.w*hv.w;
            accB[r].y += wf.x*hv.x + wf.y*hv.y + wf.z*hv.z + wf.w*hv.w;
            accB[r].z += wg.x*hv.x + wg.y*hv.y + wg.z*hv.z + wg.w*hv.w;
            accB[r].w += wo.x*hv.x + wo.y*hv.y + wo.z*hv.z + wo.w*hv.w;
        }
    }
    #pragma unroll
    for (int r=0;r<16;r++){
        size_t gn = (size_t)(row0+r);
        ushort2 uif; uif.x = f2bfu(accB[r].x); uif.y = f2bfu(accB[r].y);
        ushort2 ugo; ugo.x = f2bfu(accB[r].z); ugo.y = f2bfu(accB[r].w);
        ((ushort2*)(Pw + gn*128))[j] = uif;
        ((ushort2*)(Qw + gn*128))[j] = ugo;
    }
}

// ---------------- recurrent LSTM (8 steps, h-path only) + projection ----------------
// 256 threads, 16 rows/block. thread=(half,j): half=tid>>7 -> rows [half*8,+8),
// j=tid&127 hidden unit. acc = float4 {i,f,g,o}; gates_x preloaded from P/Q (bf16);
// Whh packed (k,j)->4 gates (wph).
__global__ __launch_bounds__(256) void lstm5(
        const float* __restrict__ gP, const float* __restrict__ gQ,
        const unsigned short* __restrict__ wph,
        const float* __restrict__ wcv, const int* __restrict__ flag,
        void* __restrict__ out){
    __shared__ float hsh[16*128];
    int tid = threadIdx.x;
    int j   = tid & 127;
    int half= tid >> 7;
    int r0  = half*8;
    int m0  = blockIdx.x * 16;
    int isf32 = flag[0];
    float c[8];
    #pragma unroll
    for (int r=0;r<8;r++) c[r]=0.f;
    for (int t=tid;t<16*128;t+=256) hsh[t] = 0.f;
    __syncthreads();
    const ushort4* wpb = (const ushort4*)wph;   // index (k*128+j)
    for (int step=0; step<8; step++){
        float4 acc[8];
        #pragma unroll
        for (int r=0;r<8;r++){
            size_t gn = (size_t)(m0 + r0 + r)*8 + step;
            ushort2 uif = ((const ushort2*)(gP + gn*128))[j];
            ushort2 ugo = ((const ushort2*)(gQ + gn*128))[j];
            acc[r].x = bfu2f(uif.x); acc[r].y = bfu2f(uif.y);
            acc[r].z = bfu2f(ugo.x); acc[r].w = bfu2f(ugo.y);
        }
        for (int k4=0;k4<32;k4++){
            const ushort4* wp = wpb + k4*4*128 + j;
            float4 w0 = cvtbf4(wp[0]);
            float4 w1 = cvtbf4(wp[128]);
            float4 w2 = cvtbf4(wp[256]);
            float4 w3 = cvtbf4(wp[384]);
            #pragma unroll
            for (int r=0;r<8;r++){
                float4 hv = *(float4*)(hsh + (r0+r)*128 + k4*4);
                acc[r].x += w0.x*hv.x + w1.x*hv.y + w2.x*hv.z + w3.x*hv.w;
                acc[r].y += w0.y*hv.x + w1.y*hv.y + w2.y*hv.z + w3.y*hv.w;
                acc[r].z += w0.z*hv.x + w1.z*hv.y + w2.z*hv.z + w3.z*hv.w;
                acc[r].w += w0.w*hv.x + w1.w*hv.y + w2.w*hv.z + w3.w*hv.w;
            }
        }
        float hreg[8];
        #pragma unroll
        for (int r=0;r<8;r++){
            float gi = sigmf(acc[r].x), gf = sigmf(acc[r].y);
            float gg = tanhfast(acc[r].z), go = sigmf(acc[r].w);
            float cc = gf*c[r] + gi*gg;
            c[r] = cc;
            hreg[r] = go*tanhfast(cc);
        }
        __syncthreads();   // all waves done reading h of this step
        #pragma unroll
        for (int r=0;r<8;r++) hsh[(r0+r)*128 + j] = hreg[r];
        __syncthreads();
    }
    // projection: out[m0+r][q] = h_last[r] . Wp[q] + bp[q]
    int r  = tid >> 4;
    int q0 = (tid & 15) * 4;
    float pacc[4];
    #pragma unroll
    for (int q=0;q<4;q++) pacc[q] = wcv[OFF_BP + q0 + q];
    for (int k4=0;k4<32;k4++){
        float4 hv = *(float4*)(hsh + r*128 + k4*4);
        #pragma unroll
        for (int q=0;q<4;q++){
            float4 wv = *(const float4*)(wcv + OFF_WP + (q0+q)*128 + k4*4);
            pacc[q] += wv.x*hv.x + wv.y*hv.y + wv.z*hv.z + wv.w*hv.w;
        }
    }
    #pragma unroll
    for (int q=0;q<4;q++){
        long o = (long)(m0+r)*64 + q0 + q;
        if (isf32) ((float*)out)[o] = pacc[q];
        else       ((__hip_bfloat16*)out)[o] = __float2bfloat16(pacc[q]);
    }
}

extern "C" void kernel_launch(void* const* d_in, const int* in_sizes, int n_in,
                              void* d_out, int out_size, void* d_ws, size_t ws_size,
                              hipStream_t stream){
    const void* x_seq      = d_in[0];
    const int*  edge_index = (const int*)d_in[1];
    const void* edge_weight= d_in[2];

    float* ws    = (float*)d_ws;
    int*   flag  = (int*)(ws + WS_FLAG);
    float* wcv   = ws + WS_WCV;
    unsigned short* wph = (unsigned short*)(ws + WS_WPH);
    float* deg_o = ws + WS_DEGO;
    float* deg_i = ws + WS_DEGI;
    int*   cnt_i = (int*)(ws + WS_CNTI);
    int*   cnt_o = (int*)(ws + WS_CNTO);
    int*   rp_i  = (int*)(ws + WS_RPI);
    int*   rp_o  = (int*)(ws + WS_RPO);
    int*   cur_i = (int*)(ws + WS_CURI);
    int*   cur_o = (int*)(ws + WS_CURO);
    int2*  csr_i = (int2*)(ws + WS_CSRI);
    int2*  csr_o = (int2*)(ws + WS_CSRO);
    float* P     = ws + WS_P;
    float* Q     = ws + WS_Q;
    __hip_bfloat16* Hb = (__hip_bfloat16*)(ws + WS_HB);

    sniff_kernel<<<1, 256, 0, stream>>>((const unsigned int*)edge_weight, flag);
    WDesc wd;
    wd.seg[0]  = { d_in[3],  OFF_W0S, 8192  };
    wd.seg[1]  = { d_in[4],  OFF_B0S, 128   };
    wd.seg[2]  = { d_in[5],  OFF_W0D, 8192  };
    wd.seg[3]  = { d_in[6],  OFF_B0D, 128   };
    wd.seg[4]  = { d_in[7],  OFF_W1S, 16384 };
    wd.seg[5]  = { d_in[8],  OFF_B1S, 128   };
    wd.seg[6]  = { d_in[9],  OFF_W1D, 16384 };
    wd.seg[7]  = { d_in[10], OFF_B1D, 128   };
    wd.seg[8]  = { d_in[11], OFF_WIH, 65536 };
    wd.seg[9]  = { d_in[12], OFF_WHH, 65536 };
    wd.seg[10] = { d_in[13], OFF_BIH, 512   };
    wd.seg[11] = { d_in[14], OFF_BHH, 512   };
    wd.seg[12] = { d_in[15], OFF_WP,  8192  };
    wd.seg[13] = { d_in[16], OFF_BP,  64    };
    convert_weights<<<(WCV_TOTAL+255)/256, 256, 0, stream>>>(wd, wcv, flag);
    repack_whh<<<256, 256, 0, stream>>>(wcv, wph);

    hist_kernel<<<G_, 1024, 0, stream>>>(edge_index, edge_weight, flag, deg_o, deg_i, cnt_i, cnt_o);
    scan_kernel<<<64, 256, 0, stream>>>(cnt_i, cnt_o, rp_i, rp_o, cur_i, cur_o);
    fill_kernel<<<(GE_+255)/256, 256, 0, stream>>>(edge_index, edge_weight, flag,
                                                   deg_o, deg_i, cur_i, cur_o, csr_i, csr_o);

    // layer 0: gather (F=64) -> P,Q ; GEMM -> Hb (bf16)
    gather64<<<2*G_*N_/4, 256, 0, stream>>>(rp_i, rp_o, csr_i, csr_o, x_seq, flag, P, Q);
    gemm_dir64<<<GN_/16, 128, 0, stream>>>(P, Q,
        wcv+OFF_W0S, wcv+OFF_B0S, wcv+OFF_W0D, wcv+OFF_B0D, Hb);

    // layer 1: gather (F=128) -> P,Q ; fused GEMM + x-gates -> bf16 in-place P,Q
    gather128<<<2*G_*N_/4, 256, 0, stream>>>(rp_i, rp_o, csr_i, csr_o, Hb, P, Q);
    gemm12<<<GN_/16, 128, 0, stream>>>(P, Q, wcv, P, Q);

    // recurrent LSTM (h-path only) + projection -> out
    lstm5<<<M_/16, 256, 0, stream>>>(P, Q, wph, wcv, flag, d_out);
}

// Round 7
// 1288.284 us; speedup vs baseline: 1.4107x; 1.4107x over previous
//
#include <hip/hip_runtime.h>
#include <hip/hip_bf16.h>

// Problem constants (B,S,N,F,H,E) = (4,8,4000,64,128,32000)
#define B_  4
#define S_  8
#define N_  4000
#define F_  64
#define H_  128
#define E_  32000
#define G_  (B_*S_)        // 32 graphs
#define GN_ (G_*N_)        // 128000 node rows
#define M_  (B_*N_)        // 16000 LSTM rows
#define GE_ (G_*E_)        // 1,024,000 edges total
#define HALF_GN 64000
#define HALF_M  8000

// f32 weight scratch offsets (floats)
#define OFF_W0S 0
#define OFF_B0S 8192
#define OFF_W0D 8320
#define OFF_B0D 16512
#define OFF_W1S 16640
#define OFF_B1S 33024
#define OFF_W1D 33152
#define OFF_B1D 49536
#define OFF_WIH 49664
#define OFF_WHH 115200
#define OFF_BIH 180736
#define OFF_BHH 181248
#define OFF_WP  181760
#define OFF_BP  189952
#define WCV_TOTAL 190016

// workspace layout (float offsets)
#define WS_FLAG   0
#define WS_WCV    16
#define WS_WPH    190032      // Whh bf16 packed: 65536 ushorts
#define WS_WPC    222800      // composed Wc bf16 [512][256]: 131072 ushorts
#define WS_BIASC  288336      // 512 f32
#define WS_DEGO   288848
#define WS_DEGI   416848
#define WS_CNTI   544848
#define WS_CNTO   672848
#define WS_RPI    800848      // 32*4001
#define WS_RPO    928880
#define WS_CURI   1056912
#define WS_CURO   1184912
#define WS_CSRI   1312912     // int2 x GE
#define WS_CSRO   3360912
#define WS_X2     5408912     // [GN][256] bf16 (P|Q concat along K)
#define WS_HB     21792912    // [GN][128] bf16
#define WS_GT     29984912    // gates half [64000][512] bf16; aliases P0,Q0 f32 [GN][64]
// end: 46,368,912 floats = 185.5 MiB (proven budget >= 193 MiB)

typedef __attribute__((ext_vector_type(8))) short bf16x8;
typedef __attribute__((ext_vector_type(4))) float f32x4;

__device__ inline float bfu2f(unsigned short u){ union{unsigned int i; float f;} v; v.i=((unsigned int)u)<<16; return v.f; }
__device__ inline unsigned short f2bfu(float f){ __hip_bfloat16 b = __float2bfloat16(f); return *(unsigned short*)&b; }
__device__ inline float rcpf(float x){ return __builtin_amdgcn_rcpf(x); }
__device__ inline float sigmf(float x){ return rcpf(1.0f + __expf(-x)); }
__device__ inline float tanhfast(float x){ return 1.0f - 2.0f*rcpf(1.0f + __expf(2.0f*x)); }
__device__ inline float loadf(const void* p, long i, int isf32){
    return isf32 ? ((const float*)p)[i]
                 : __bfloat162float(((const __hip_bfloat16*)p)[i]);
}
__device__ inline float4 cvtbf4(ushort4 u){
    float4 f;
    f.x = __uint_as_float(((unsigned)u.x)<<16);
    f.y = __uint_as_float(((unsigned)u.y)<<16);
    f.z = __uint_as_float(((unsigned)u.z)<<16);
    f.w = __uint_as_float(((unsigned)u.w)<<16);
    return f;
}

// ---------------- dtype sniff (inputs f32 vs bf16) ----------------
__global__ void sniff_kernel(const unsigned int* __restrict__ ew, int* __restrict__ flag){
    __shared__ int s;
    if (threadIdx.x == 0) s = 0;
    __syncthreads();
    unsigned int lo = ew[threadIdx.x] & 0xFFFFu;
    if (lo > 0x3F80u) atomicOr(&s, 1);
    __syncthreads();
    if (threadIdx.x == 0) flag[0] = s;   // 1 => inputs are f32
}

// ---------------- weight conversion to f32 scratch ----------------
struct WSeg { const void* src; int base; int n; };
struct WDesc { WSeg seg[14]; };
__global__ void convert_weights(WDesc d, float* __restrict__ dst, const int* __restrict__ flag){
    int isf32 = flag[0];
    int idx = blockIdx.x*256 + threadIdx.x;
    #pragma unroll
    for (int s=0;s<14;s++){
        int off = idx - d.seg[s].base;
        if (off >= 0 && off < d.seg[s].n){
            dst[idx] = loadf(d.seg[s].src, off, isf32);
            return;
        }
    }
}

// ---------------- Whh repack: wph[(k*128+j)*4+g] = bf16 Whh[g*128+j][k] ----------------
__global__ void repack_whh(const float* __restrict__ wcv, unsigned short* __restrict__ wph){
    int idx = blockIdx.x*256 + threadIdx.x;   // < 65536
    int g = idx & 3;
    int j = (idx>>2) & 127;
    int k = idx >> 9;
    wph[idx] = f2bfu(wcv[OFF_WHH + (g*128+j)*128 + k]);
}

// ---------------- composed weights: Wc[n][k] bf16 [512][256] ----------------
// k<128: 0.5*sum_h Wih[n][h]*W1s[h][k] ; k>=128: 0.5*sum_h Wih[n][h]*W1d[h][k-128]
__global__ __launch_bounds__(256) void compose_wc(const float* __restrict__ wcv,
                                                  unsigned short* __restrict__ wpc){
    int n = blockIdx.x;        // 512 blocks
    int k = threadIdx.x;       // 256
    const float* wih = wcv + OFF_WIH + n*128;
    const float* w1  = (k < 128) ? (wcv + OFF_W1S + k) : (wcv + OFF_W1D + (k-128));
    float s = 0.f;
    for (int h=0; h<128; h++) s += wih[h] * w1[h*128];
    wpc[n*256 + k] = f2bfu(0.5f * s);
}

// biasc[n] = bih[n]+bhh[n] + sum_h Wih[n][h]*0.5*(b1s[h]+b1d[h])
__global__ void compose_bias(const float* __restrict__ wcv, float* __restrict__ biasc){
    int n = blockIdx.x*256 + threadIdx.x;
    if (n >= 512) return;
    float s = wcv[OFF_BIH+n] + wcv[OFF_BHH+n];
    const float* wih = wcv + OFF_WIH + n*128;
    for (int h=0; h<128; h++) s += wih[h] * 0.5f*(wcv[OFF_B1S+h] + wcv[OFF_B1D+h]);
    biasc[n] = s;
}

// ---------------- per-graph histogram: weighted degrees + counts ----------------
__global__ __launch_bounds__(1024) void hist_kernel(
        const int* __restrict__ ei, const void* __restrict__ ew, const int* __restrict__ flag,
        float* __restrict__ deg_o, float* __restrict__ deg_i,
        int* __restrict__ cnt_in, int* __restrict__ cnt_out){
    __shared__ float wdo[N_], wdi[N_];
    __shared__ int   co[N_],  ci[N_];
    int g = blockIdx.x, tid = threadIdx.x;
    int isf32 = flag[0];
    for (int i=tid;i<N_;i+=1024){ wdo[i]=0.f; wdi[i]=0.f; co[i]=0; ci[i]=0; }
    __syncthreads();
    const int* eib = ei + g*2*E_;
    for (int e=tid;e<E_;e+=1024){
        int s = eib[e], d = eib[E_+e];
        float w = loadf(ew, (long)g*E_+e, isf32);
        atomicAdd(&wdo[s], w); atomicAdd(&wdi[d], w);
        atomicAdd(&co[s], 1);  atomicAdd(&ci[d], 1);
    }
    __syncthreads();
    for (int i=tid;i<N_;i+=1024){
        deg_o[g*N_+i]=wdo[i]; deg_i[g*N_+i]=wdi[i];
        cnt_out[g*N_+i]=co[i]; cnt_in[g*N_+i]=ci[i];
    }
}

// ---------------- exclusive scan -> row_ptr + cursors ----------------
__global__ __launch_bounds__(256) void scan_kernel(
        const int* __restrict__ cnt_in, const int* __restrict__ cnt_out,
        int* __restrict__ rp_in, int* __restrict__ rp_out,
        int* __restrict__ cur_in, int* __restrict__ cur_out){
    __shared__ int part[256], pref[256];
    int g = blockIdx.x & 31, dir = blockIdx.x >> 5;
    const int* cnt = (dir ? cnt_out : cnt_in) + g*N_;
    int* rp  = (dir ? rp_out  : rp_in)  + g*(N_+1);
    int* cur = (dir ? cur_out : cur_in) + g*N_;
    int tid = threadIdx.x, base = tid*16;
    int sum = 0;
    for (int i=0;i<16;i++){ int p = base+i; if (p < N_) sum += cnt[p]; }
    part[tid] = sum;
    __syncthreads();
    if (tid == 0){ int run = 0; for (int j=0;j<256;j++){ pref[j] = run; run += part[j]; } }
    __syncthreads();
    int run = pref[tid];
    for (int i=0;i<16;i++){
        int p = base+i;
        if (p < N_){ rp[p] = run; cur[p] = run; run += cnt[p]; }
    }
    if (tid == 255) rp[N_] = run;
}

// ---------------- fill CSR ----------------
__global__ void fill_kernel(const int* __restrict__ ei, const void* __restrict__ ew,
                            const int* __restrict__ flag,
                            const float* __restrict__ deg_o, const float* __restrict__ deg_i,
                            int* __restrict__ cur_in, int* __restrict__ cur_out,
                            int2* __restrict__ csr_in, int2* __restrict__ csr_out){
    int idx = blockIdx.x*256 + threadIdx.x;
    if (idx >= GE_) return;
    int isf32 = flag[0];
    int g = idx / E_, e = idx - g*E_;
    const int* eib = ei + g*2*E_;
    int s = eib[e], d = eib[E_ + e];
    float dout = deg_o[g*N_+s], din = deg_i[g*N_+d];
    float io = dout > 0.f ? rsqrtf(fmaxf(dout, 1e-12f)) : 0.f;
    float ii = din  > 0.f ? rsqrtf(fmaxf(din , 1e-12f)) : 0.f;
    float nrm = loadf(ew, idx, isf32) * io * ii;
    int p1 = atomicAdd(&cur_in[g*N_+d], 1);
    csr_in[(long)g*E_ + p1] = make_int2(s, __float_as_int(nrm));
    int p2 = atomicAdd(&cur_out[g*N_+s], 1);
    csr_out[(long)g*E_ + p2] = make_int2(d, __float_as_int(nrm));
}

// ---------------- gather layer 0: one wave per (g,dir,node), F=64 ----------------
__global__ void gather64(const int* __restrict__ rp_in, const int* __restrict__ rp_out,
                         const int2* __restrict__ csr_in, const int2* __restrict__ csr_out,
                         const void* __restrict__ x, const int* __restrict__ flag,
                         float* __restrict__ P, float* __restrict__ Q){
    int isf32 = flag[0];
    int wid = blockIdx.x*4 + (threadIdx.x>>6);
    int lane = threadIdx.x & 63;
    int g = wid / (2*N_); int rem = wid - g*(2*N_);
    int dir = rem / N_;   int n = rem - dir*N_;
    const int*  rp  = (dir ? rp_out : rp_in) + g*(N_+1);
    const int2* csr = (dir ? csr_out : csr_in) + (long)g*E_;
    int pb = rp[n], pe = rp[n+1];
    float acc = 0.f;
    for (int p=pb; p<pe; p++){
        int2 ent = csr[p];
        float w = __int_as_float(ent.y);
        acc += w * loadf(x, ((long)(g*N_+ent.x))*64 + lane, isf32);
    }
    float* o = dir ? Q : P;
    o[((long)(g*N_+n))*64 + lane] = acc;
}

// ---------------- gather layer 1 -> X2 bf16 [GN][256] (dir0 cols 0..127, dir1 128..255) ----------------
__global__ void gather128(const int* __restrict__ rp_in, const int* __restrict__ rp_out,
                          const int2* __restrict__ csr_in, const int2* __restrict__ csr_out,
                          const __hip_bfloat16* __restrict__ hb,
                          unsigned short* __restrict__ X2){
    int wid = blockIdx.x*4 + (threadIdx.x>>6);
    int lane = threadIdx.x & 63;
    int g = wid / (2*N_); int rem = wid - g*(2*N_);
    int dir = rem / N_;   int n = rem - dir*N_;
    const int*  rp  = (dir ? rp_out : rp_in) + g*(N_+1);
    const int2* csr = (dir ? csr_out : csr_in) + (long)g*E_;
    int pb = rp[n], pe = rp[n+1];
    float2 acc = make_float2(0.f, 0.f);
    for (int p=pb; p<pe; p++){
        int2 ent = csr[p];
        float w = __int_as_float(ent.y);
        ushort2 u = ((const ushort2*)(hb + ((long)(g*N_+ent.x))*128))[lane];
        acc.x += w*bfu2f(u.x); acc.y += w*bfu2f(u.y);
    }
    ushort2 o; o.x = f2bfu(acc.x); o.y = f2bfu(acc.y);
    ((ushort2*)(X2 + (size_t)(g*N_+n)*256 + dir*128))[lane] = o;
}

// --------- layer-0 GEMM: Hb(bf16) = 0.5*(P@W0s^T+b0s) + 0.5*(Q@W0d^T+b0d) ---------
__global__ __launch_bounds__(128) void gemm_dir64(
        const float* __restrict__ Afb, const float* __restrict__ Abb,
        const float* __restrict__ Ws, const float* __restrict__ bs,
        const float* __restrict__ Wd, const float* __restrict__ bd,
        __hip_bfloat16* __restrict__ out){
    __shared__ float4 Af[16][16];
    __shared__ float4 Ab[16][16];
    int j = threadIdx.x;
    int row0 = blockIdx.x * 16;
    const float4* Af_g = (const float4*)(Afb + (size_t)row0*64);
    const float4* Ab_g = (const float4*)(Abb + (size_t)row0*64);
    for (int t = j; t < 16*16; t += 128) {
        ((float4*)Af)[t] = Af_g[t];
        ((float4*)Ab)[t] = Ab_g[t];
    }
    __syncthreads();
    float acc[16];
    #pragma unroll
    for (int r=0;r<16;r++) acc[r]=0.f;
    const float4* Wsv = (const float4*)(Ws + j*64);
    const float4* Wdv = (const float4*)(Wd + j*64);
    for (int k4=0;k4<16;k4++){
        float4 a = Wsv[k4];
        float4 b = Wdv[k4];
        #pragma unroll
        for (int r=0;r<16;r++){
            float4 fa = Af[r][k4];
            float4 fb = Ab[r][k4];
            acc[r] += a.x*fa.x + a.y*fa.y + a.z*fa.z + a.w*fa.w
                    + b.x*fb.x + b.y*fb.y + b.z*fb.z + b.w*fb.w;
        }
    }
    float bias = 0.5f*(bs[j] + bd[j]);
    #pragma unroll
    for (int r=0;r<16;r++) out[(size_t)(row0+r)*128 + j] = __float2bfloat16(0.5f*acc[r] + bias);
}

// ---------------- MFMA gates GEMM: gates[64000][512] = X2[gn_base+..][256] @ Wc^T + biasc ----------------
// block 256 threads = 4 waves. Tile 64 rows x 64 cols. B-frags in registers
// (per wave: its 16 cols, all K=256). A staged via double-buffered padded LDS.
__global__ __launch_bounds__(256) void gemmg(
        const unsigned short* __restrict__ X2, const unsigned short* __restrict__ wpc,
        const float* __restrict__ biasc, unsigned short* __restrict__ gates, int gn_base){
    __shared__ unsigned short As[2][64*40];   // stride 40 ushorts (80B) -> 2-way bank alias (free)
    int tid  = threadIdx.x;
    int wave = tid >> 6, lane = tid & 63;
    int quad = lane >> 4, l16 = lane & 15;
    int nb = blockIdx.x & 7, mb = blockIdx.x >> 3;
    int m0 = mb*64;
    int col = nb*64 + wave*16 + l16;
    bf16x8 bq[8];
    #pragma unroll
    for (int ks=0; ks<8; ks++)
        bq[ks] = *(const bf16x8*)(wpc + (size_t)col*256 + ks*32 + quad*8);
    f32x4 acc[4];
    #pragma unroll
    for (int t=0;t<4;t++) acc[t] = (f32x4){0.f,0.f,0.f,0.f};
    int srow = tid>>2, sch = tid&3;
    const unsigned short* src_base = X2 + (size_t)(gn_base + m0 + srow)*256 + sch*8;
    // stage ks=0
    *(float4*)(&As[0][srow*40 + sch*8]) = *(const float4*)(src_base);
    __syncthreads();
    for (int ks=0; ks<8; ks++){
        if (ks < 7)
            *(float4*)(&As[(ks+1)&1][srow*40 + sch*8]) = *(const float4*)(src_base + (ks+1)*32);
        const unsigned short* ab = As[ks&1];
        #pragma unroll
        for (int t=0;t<4;t++){
            bf16x8 a = *(const bf16x8*)(ab + (t*16 + l16)*40 + quad*8);
            acc[t] = __builtin_amdgcn_mfma_f32_16x16x32_bf16(a, bq[ks], acc[t], 0, 0, 0);
        }
        __syncthreads();
    }
    float bc = biasc[col];
    #pragma unroll
    for (int t=0;t<4;t++){
        #pragma unroll
        for (int r=0;r<4;r++){
            int grow = m0 + t*16 + quad*4 + r;
            gates[(size_t)grow*512 + col] = f2bfu(acc[t][r] + bc);
        }
    }
}

// ---------------- recurrent LSTM (8 steps, h-path) + projection ----------------
// gates: bf16 [rows local to half][512], layout i|f|g|o blocks of 128.
// gn_base = first GLOBAL gate row held in this gates buffer (= HALF_GN for half 2).
__global__ __launch_bounds__(256) void lstm6(
        const unsigned short* __restrict__ gates, long gn_base, int mbase,
        const unsigned short* __restrict__ wph,
        const float* __restrict__ wcv, const int* __restrict__ flag,
        void* __restrict__ out){
    __shared__ float hsh[16*128];
    int tid = threadIdx.x;
    int j   = tid & 127;
    int half= tid >> 7;
    int r0  = half*8;
    int m0  = mbase + blockIdx.x * 16;
    int isf32 = flag[0];
    float c[8];
    #pragma unroll
    for (int r=0;r<8;r++) c[r]=0.f;
    for (int t=tid;t<16*128;t+=256) hsh[t] = 0.f;
    __syncthreads();
    const ushort4* wpb = (const ushort4*)wph;
    for (int step=0; step<8; step++){
        float4 acc[8];
        #pragma unroll
        for (int r=0;r<8;r++){
            size_t gl = ((size_t)(m0 + r0 + r)*8 + step) - gn_base;
            const unsigned short* gr = gates + gl*512;
            acc[r].x = bfu2f(gr[      j]);
            acc[r].y = bfu2f(gr[128 + j]);
            acc[r].z = bfu2f(gr[256 + j]);
            acc[r].w = bfu2f(gr[384 + j]);
        }
        for (int k4=0;k4<32;k4++){
            const ushort4* wp = wpb + k4*4*128 + j;
            float4 w0 = cvtbf4(wp[0]);
            float4 w1 = cvtbf4(wp[128]);
            float4 w2 = cvtbf4(wp[256]);
            float4 w3 = cvtbf4(wp[384]);
            #pragma unroll
            for (int r=0;r<8;r++){
                float4 hv = *(float4*)(hsh + (r0+r)*128 + k4*4);
                acc[r].x += w0.x*hv.x + w1.x*hv.y + w2.x*hv.z + w3.x*hv.w;
                acc[r].y += w0.y*hv.x + w1.y*hv.y + w2.y*hv.z + w3.y*hv.w;
                acc[r].z += w0.z*hv.x + w1.z*hv.y + w2.z*hv.z + w3.z*hv.w;
                acc[r].w += w0.w*hv.x + w1.w*hv.y + w2.w*hv.z + w3.w*hv.w;
            }
        }
        float hreg[8];
        #pragma unroll
        for (int r=0;r<8;r++){
            float gi = sigmf(acc[r].x), gf = sigmf(acc[r].y);
            float gg = tanhfast(acc[r].z), go = sigmf(acc[r].w);
            float cc = gf*c[r] + gi*gg;
            c[r] = cc;
            hreg[r] = go*tanhfast(cc);
        }
        __syncthreads();
        #pragma unroll
        for (int r=0;r<8;r++) hsh[(r0+r)*128 + j] = hreg[r];
        __syncthreads();
    }
    int r  = tid >> 4;
    int q0 = (tid & 15) * 4;
    float pacc[4];
    #pragma unroll
    for (int q=0;q<4;q++) pacc[q] = wcv[OFF_BP + q0 + q];
    for (int k4=0;k4<32;k4++){
        float4 hv = *(float4*)(hsh + r*128 + k4*4);
        #pragma unroll
        for (int q=0;q<4;q++){
            float4 wv = *(const float4*)(wcv + OFF_WP + (q0+q)*128 + k4*4);
            pacc[q] += wv.x*hv.x + wv.y*hv.y + wv.z*hv.z + wv.w*hv.w;
        }
    }
    #pragma unroll
    for (int q=0;q<4;q++){
        long o = (long)(m0+r)*64 + q0 + q;
        if (isf32) ((float*)out)[o] = pacc[q];
        else       ((__hip_bfloat16*)out)[o] = __float2bfloat16(pacc[q]);
    }
}

extern "C" void kernel_launch(void* const* d_in, const int* in_sizes, int n_in,
                              void* d_out, int out_size, void* d_ws, size_t ws_size,
                              hipStream_t stream){
    const void* x_seq      = d_in[0];
    const int*  edge_index = (const int*)d_in[1];
    const void* edge_weight= d_in[2];

    float* ws    = (float*)d_ws;
    int*   flag  = (int*)(ws + WS_FLAG);
    float* wcv   = ws + WS_WCV;
    unsigned short* wph = (unsigned short*)(ws + WS_WPH);
    unsigned short* wpc = (unsigned short*)(ws + WS_WPC);
    float* biasc = ws + WS_BIASC;
    float* deg_o = ws + WS_DEGO;
    float* deg_i = ws + WS_DEGI;
    int*   cnt_i = (int*)(ws + WS_CNTI);
    int*   cnt_o = (int*)(ws + WS_CNTO);
    int*   rp_i  = (int*)(ws + WS_RPI);
    int*   rp_o  = (int*)(ws + WS_RPO);
    int*   cur_i = (int*)(ws + WS_CURI);
    int*   cur_o = (int*)(ws + WS_CURO);
    int2*  csr_i = (int2*)(ws + WS_CSRI);
    int2*  csr_o = (int2*)(ws + WS_CSRO);
    unsigned short* X2 = (unsigned short*)(ws + WS_X2);
    __hip_bfloat16* Hb = (__hip_bfloat16*)(ws + WS_HB);
    unsigned short* GT = (unsigned short*)(ws + WS_GT);
    float* P0 = ws + WS_GT;              // aliases GT (dead before gates written)
    float* Q0 = P0 + (size_t)GN_*64;

    sniff_kernel<<<1, 256, 0, stream>>>((const unsigned int*)edge_weight, flag);
    WDesc wd;
    wd.seg[0]  = { d_in[3],  OFF_W0S, 8192  };
    wd.seg[1]  = { d_in[4],  OFF_B0S, 128   };
    wd.seg[2]  = { d_in[5],  OFF_W0D, 8192  };
    wd.seg[3]  = { d_in[6],  OFF_B0D, 128   };
    wd.seg[4]  = { d_in[7],  OFF_W1S, 16384 };
    wd.seg[5]  = { d_in[8],  OFF_B1S, 128   };
    wd.seg[6]  = { d_in[9],  OFF_W1D, 16384 };
    wd.seg[7]  = { d_in[10], OFF_B1D, 128   };
    wd.seg[8]  = { d_in[11], OFF_WIH, 65536 };
    wd.seg[9]  = { d_in[12], OFF_WHH, 65536 };
    wd.seg[10] = { d_in[13], OFF_BIH, 512   };
    wd.seg[11] = { d_in[14], OFF_BHH, 512   };
    wd.seg[12] = { d_in[15], OFF_WP,  8192  };
    wd.seg[13] = { d_in[16], OFF_BP,  64    };
    convert_weights<<<(WCV_TOTAL+255)/256, 256, 0, stream>>>(wd, wcv, flag);
    repack_whh<<<256, 256, 0, stream>>>(wcv, wph);
    compose_wc<<<512, 256, 0, stream>>>(wcv, wpc);
    compose_bias<<<2, 256, 0, stream>>>(wcv, biasc);

    hist_kernel<<<G_, 1024, 0, stream>>>(edge_index, edge_weight, flag, deg_o, deg_i, cnt_i, cnt_o);
    scan_kernel<<<64, 256, 0, stream>>>(cnt_i, cnt_o, rp_i, rp_o, cur_i, cur_o);
    fill_kernel<<<(GE_+255)/256, 256, 0, stream>>>(edge_index, edge_weight, flag,
                                                   deg_o, deg_i, cur_i, cur_o, csr_i, csr_o);

    // layer 0: gather -> P0,Q0 (in GT region); GEMM -> Hb (bf16)
    gather64<<<2*G_*N_/4, 256, 0, stream>>>(rp_i, rp_o, csr_i, csr_o, x_seq, flag, P0, Q0);
    gemm_dir64<<<GN_/16, 128, 0, stream>>>(P0, Q0,
        wcv+OFF_W0S, wcv+OFF_B0S, wcv+OFF_W0D, wcv+OFF_B0D, Hb);

    // layer 1: gather -> X2 (bf16); then per-half: MFMA gates GEMM + LSTM
    gather128<<<2*G_*N_/4, 256, 0, stream>>>(rp_i, rp_o, csr_i, csr_o, Hb, X2);

    gemmg<<<8*(HALF_GN/64), 256, 0, stream>>>(X2, wpc, biasc, GT, 0);
    lstm6<<<HALF_M/16, 256, 0, stream>>>(GT, 0L, 0, wph, wcv, flag, d_out);

    gemmg<<<8*(HALF_GN/64), 256, 0, stream>>>(X2, wpc, biasc, GT, HALF_GN);
    // gates buffer's first global gate row is HALF_GN (= HALF_M*8). Round-6 bug:
    // this was HALF_GN*8 (=512000) -> size_t underflow -> OOB -> device abort.
    lstm6<<<HALF_M/16, 256, 0, stream>>>(GT, (long)HALF_GN, HALF_M, wph, wcv, flag, d_out);
}

// Round 8
// 1035.743 us; speedup vs baseline: 1.7546x; 1.2438x over previous
//
#include <hip/hip_runtime.h>
#include <hip/hip_bf16.h>

// Problem constants (B,S,N,F,H,E) = (4,8,4000,64,128,32000)
#define B_  4
#define S_  8
#define N_  4000
#define F_  64
#define H_  128
#define E_  32000
#define G_  (B_*S_)        // 32 graphs
#define GN_ (G_*N_)        // 128000 node rows
#define M_  (B_*N_)        // 16000 LSTM rows
#define GE_ (G_*E_)        // 1,024,000 edges total
#define HALF_GN 64000
#define HALF_M  8000

// f32 weight scratch offsets (floats)
#define OFF_W0S 0
#define OFF_B0S 8192
#define OFF_W0D 8320
#define OFF_B0D 16512
#define OFF_W1S 16640
#define OFF_B1S 33024
#define OFF_W1D 33152
#define OFF_B1D 49536
#define OFF_WIH 49664
#define OFF_WHH 115200
#define OFF_BIH 180736
#define OFF_BHH 181248
#define OFF_WP  181760
#define OFF_BP  189952
#define WCV_TOTAL 190016

// workspace layout (float offsets)
#define WS_FLAG   0
#define WS_WCV    16
#define WS_WPH    190032      // Whh bf16 [512][128]: 65536 ushorts
#define WS_WPC    222800      // composed Wc bf16 [512][256]: 131072 ushorts
#define WS_BIASC  288336      // 512 f32
#define WS_DEGO   288848
#define WS_DEGI   416848
#define WS_CNTI   544848
#define WS_CNTO   672848
#define WS_RPI    800848      // 32*4001
#define WS_RPO    928880
#define WS_CURI   1056912
#define WS_CURO   1184912
#define WS_CSRI   1312912     // int2 x GE
#define WS_CSRO   3360912
#define WS_X2     5408912     // [GN][256] bf16; first 8.2M ushorts alias Xb [GN][64] bf16
#define WS_HB     21792912    // [GN][128] bf16
#define WS_GT     29984912    // gates half [64000][512] bf16; aliases P0,Q0 f32 [GN][64]
// end: 46,368,912 floats = 185.5 MiB (proven budget >= 193 MiB)

typedef __attribute__((ext_vector_type(8))) short bf16x8;
typedef __attribute__((ext_vector_type(4))) float f32x4;

__device__ inline float bfu2f(unsigned short u){ union{unsigned int i; float f;} v; v.i=((unsigned int)u)<<16; return v.f; }
__device__ inline unsigned short f2bfu(float f){ __hip_bfloat16 b = __float2bfloat16(f); return *(unsigned short*)&b; }
__device__ inline float rcpf(float x){ return __builtin_amdgcn_rcpf(x); }
__device__ inline float sigmf(float x){ return rcpf(1.0f + __expf(-x)); }
__device__ inline float tanhfast(float x){ return 1.0f - 2.0f*rcpf(1.0f + __expf(2.0f*x)); }
__device__ inline float loadf(const void* p, long i, int isf32){
    return isf32 ? ((const float*)p)[i]
                 : __bfloat162float(((const __hip_bfloat16*)p)[i]);
}
__device__ inline float4 cvtbf4(ushort4 u){
    float4 f;
    f.x = __uint_as_float(((unsigned)u.x)<<16);
    f.y = __uint_as_float(((unsigned)u.y)<<16);
    f.z = __uint_as_float(((unsigned)u.z)<<16);
    f.w = __uint_as_float(((unsigned)u.w)<<16);
    return f;
}

// ---------------- dtype sniff (inputs f32 vs bf16) ----------------
__global__ void sniff_kernel(const unsigned int* __restrict__ ew, int* __restrict__ flag){
    __shared__ int s;
    if (threadIdx.x == 0) s = 0;
    __syncthreads();
    unsigned int lo = ew[threadIdx.x] & 0xFFFFu;
    if (lo > 0x3F80u) atomicOr(&s, 1);
    __syncthreads();
    if (threadIdx.x == 0) flag[0] = s;   // 1 => inputs are f32
}

// ---------------- weight conversion to f32 scratch ----------------
struct WSeg { const void* src; int base; int n; };
struct WDesc { WSeg seg[14]; };
__global__ void convert_weights(WDesc d, float* __restrict__ dst, const int* __restrict__ flag){
    int isf32 = flag[0];
    int idx = blockIdx.x*256 + threadIdx.x;
    #pragma unroll
    for (int s=0;s<14;s++){
        int off = idx - d.seg[s].base;
        if (off >= 0 && off < d.seg[s].n){
            dst[idx] = loadf(d.seg[s].src, off, isf32);
            return;
        }
    }
}

// ---------------- Whh bf16 copy: whb[r*128+k] = bf16(Whh[r][k]) ----------------
__global__ void repack_whh(const float* __restrict__ wcv, unsigned short* __restrict__ whb){
    int idx = blockIdx.x*256 + threadIdx.x;   // < 65536
    whb[idx] = f2bfu(wcv[OFF_WHH + idx]);
}

// ---------------- x_seq -> bf16 Xb [GN][64] ----------------
__global__ void xcvt_kernel(const void* __restrict__ x, const int* __restrict__ flag,
                            unsigned short* __restrict__ Xb){
    long idx = (long)blockIdx.x*256 + threadIdx.x;
    if (idx >= (long)GN_*64) return;
    Xb[idx] = f2bfu(loadf(x, idx, flag[0]));
}

// ---------------- composed weights: Wc[n][k] bf16 [512][256] ----------------
__global__ __launch_bounds__(256) void compose_wc(const float* __restrict__ wcv,
                                                  unsigned short* __restrict__ wpc){
    int n = blockIdx.x;        // 512 blocks
    int k = threadIdx.x;       // 256
    const float* wih = wcv + OFF_WIH + n*128;
    const float* w1  = (k < 128) ? (wcv + OFF_W1S + k) : (wcv + OFF_W1D + (k-128));
    float s = 0.f;
    for (int h=0; h<128; h++) s += wih[h] * w1[h*128];
    wpc[n*256 + k] = f2bfu(0.5f * s);
}

// biasc[n] = bih[n]+bhh[n] + sum_h Wih[n][h]*0.5*(b1s[h]+b1d[h])
__global__ void compose_bias(const float* __restrict__ wcv, float* __restrict__ biasc){
    int n = blockIdx.x*256 + threadIdx.x;
    if (n >= 512) return;
    float s = wcv[OFF_BIH+n] + wcv[OFF_BHH+n];
    const float* wih = wcv + OFF_WIH + n*128;
    for (int h=0; h<128; h++) s += wih[h] * 0.5f*(wcv[OFF_B1S+h] + wcv[OFF_B1D+h]);
    biasc[n] = s;
}

// ---------------- per-graph histogram: weighted degrees + counts ----------------
__global__ __launch_bounds__(1024) void hist_kernel(
        const int* __restrict__ ei, const void* __restrict__ ew, const int* __restrict__ flag,
        float* __restrict__ deg_o, float* __restrict__ deg_i,
        int* __restrict__ cnt_in, int* __restrict__ cnt_out){
    __shared__ float wdo[N_], wdi[N_];
    __shared__ int   co[N_],  ci[N_];
    int g = blockIdx.x, tid = threadIdx.x;
    int isf32 = flag[0];
    for (int i=tid;i<N_;i+=1024){ wdo[i]=0.f; wdi[i]=0.f; co[i]=0; ci[i]=0; }
    __syncthreads();
    const int* eib = ei + g*2*E_;
    for (int e=tid;e<E_;e+=1024){
        int s = eib[e], d = eib[E_+e];
        float w = loadf(ew, (long)g*E_+e, isf32);
        atomicAdd(&wdo[s], w); atomicAdd(&wdi[d], w);
        atomicAdd(&co[s], 1);  atomicAdd(&ci[d], 1);
    }
    __syncthreads();
    for (int i=tid;i<N_;i+=1024){
        deg_o[g*N_+i]=wdo[i]; deg_i[g*N_+i]=wdi[i];
        cnt_out[g*N_+i]=co[i]; cnt_in[g*N_+i]=ci[i];
    }
}

// ---------------- exclusive scan -> row_ptr + cursors ----------------
__global__ __launch_bounds__(256) void scan_kernel(
        const int* __restrict__ cnt_in, const int* __restrict__ cnt_out,
        int* __restrict__ rp_in, int* __restrict__ rp_out,
        int* __restrict__ cur_in, int* __restrict__ cur_out){
    __shared__ int part[256], pref[256];
    int g = blockIdx.x & 31, dir = blockIdx.x >> 5;
    const int* cnt = (dir ? cnt_out : cnt_in) + g*N_;
    int* rp  = (dir ? rp_out  : rp_in)  + g*(N_+1);
    int* cur = (dir ? cur_out : cur_in) + g*N_;
    int tid = threadIdx.x, base = tid*16;
    int sum = 0;
    for (int i=0;i<16;i++){ int p = base+i; if (p < N_) sum += cnt[p]; }
    part[tid] = sum;
    __syncthreads();
    if (tid == 0){ int run = 0; for (int j=0;j<256;j++){ pref[j] = run; run += part[j]; } }
    __syncthreads();
    int run = pref[tid];
    for (int i=0;i<16;i++){
        int p = base+i;
        if (p < N_){ rp[p] = run; cur[p] = run; run += cnt[p]; }
    }
    if (tid == 255) rp[N_] = run;
}

// ---------------- fill CSR ----------------
__global__ void fill_kernel(const int* __restrict__ ei, const void* __restrict__ ew,
                            const int* __restrict__ flag,
                            const float* __restrict__ deg_o, const float* __restrict__ deg_i,
                            int* __restrict__ cur_in, int* __restrict__ cur_out,
                            int2* __restrict__ csr_in, int2* __restrict__ csr_out){
    int idx = blockIdx.x*256 + threadIdx.x;
    if (idx >= GE_) return;
    int isf32 = flag[0];
    int g = idx / E_, e = idx - g*E_;
    const int* eib = ei + g*2*E_;
    int s = eib[e], d = eib[E_ + e];
    float dout = deg_o[g*N_+s], din = deg_i[g*N_+d];
    float io = dout > 0.f ? rsqrtf(fmaxf(dout, 1e-12f)) : 0.f;
    float ii = din  > 0.f ? rsqrtf(fmaxf(din , 1e-12f)) : 0.f;
    float nrm = loadf(ew, idx, isf32) * io * ii;
    int p1 = atomicAdd(&cur_in[g*N_+d], 1);
    csr_in[(long)g*E_ + p1] = make_int2(s, __float_as_int(nrm));
    int p2 = atomicAdd(&cur_out[g*N_+s], 1);
    csr_out[(long)g*E_ + p2] = make_int2(d, __float_as_int(nrm));
}

// ---------------- gather layer 0: one wave per (g,dir,node), bf16 Xb, F=64 ----------------
__global__ void gather64(const int* __restrict__ rp_in, const int* __restrict__ rp_out,
                         const int2* __restrict__ csr_in, const int2* __restrict__ csr_out,
                         const unsigned short* __restrict__ Xb,
                         float* __restrict__ P, float* __restrict__ Q){
    int wid = blockIdx.x*4 + (threadIdx.x>>6);
    int lane = threadIdx.x & 63;
    int g = wid / (2*N_); int rem = wid - g*(2*N_);
    int dir = rem / N_;   int n = rem - dir*N_;
    const int*  rp  = (dir ? rp_out : rp_in) + g*(N_+1);
    const int2* csr = (dir ? csr_out : csr_in) + (long)g*E_;
    int pb = rp[n], pe = rp[n+1];
    float acc = 0.f;
    for (int p=pb; p<pe; p++){
        int2 ent = csr[p];
        float w = __int_as_float(ent.y);
        acc += w * bfu2f(Xb[((long)(g*N_+ent.x))*64 + lane]);
    }
    float* o = dir ? Q : P;
    o[((long)(g*N_+n))*64 + lane] = acc;
}

// ---------------- gather layer 1 -> X2 bf16 [GN][256] ----------------
__global__ void gather128(const int* __restrict__ rp_in, const int* __restrict__ rp_out,
                          const int2* __restrict__ csr_in, const int2* __restrict__ csr_out,
                          const __hip_bfloat16* __restrict__ hb,
                          unsigned short* __restrict__ X2){
    int wid = blockIdx.x*4 + (threadIdx.x>>6);
    int lane = threadIdx.x & 63;
    int g = wid / (2*N_); int rem = wid - g*(2*N_);
    int dir = rem / N_;   int n = rem - dir*N_;
    const int*  rp  = (dir ? rp_out : rp_in) + g*(N_+1);
    const int2* csr = (dir ? csr_out : csr_in) + (long)g*E_;
    int pb = rp[n], pe = rp[n+1];
    float2 acc = make_float2(0.f, 0.f);
    for (int p=pb; p<pe; p++){
        int2 ent = csr[p];
        float w = __int_as_float(ent.y);
        ushort2 u = ((const ushort2*)(hb + ((long)(g*N_+ent.x))*128))[lane];
        acc.x += w*bfu2f(u.x); acc.y += w*bfu2f(u.y);
    }
    ushort2 o; o.x = f2bfu(acc.x); o.y = f2bfu(acc.y);
    ((ushort2*)(X2 + (size_t)(g*N_+n)*256 + dir*128))[lane] = o;
}

// --------- layer-0 GEMM: Hb(bf16) = 0.5*(P@W0s^T+b0s) + 0.5*(Q@W0d^T+b0d) ---------
__global__ __launch_bounds__(128) void gemm_dir64(
        const float* __restrict__ Afb, const float* __restrict__ Abb,
        const float* __restrict__ Ws, const float* __restrict__ bs,
        const float* __restrict__ Wd, const float* __restrict__ bd,
        __hip_bfloat16* __restrict__ out){
    __shared__ float4 Af[16][16];
    __shared__ float4 Ab[16][16];
    int j = threadIdx.x;
    int row0 = blockIdx.x * 16;
    const float4* Af_g = (const float4*)(Afb + (size_t)row0*64);
    const float4* Ab_g = (const float4*)(Abb + (size_t)row0*64);
    for (int t = j; t < 16*16; t += 128) {
        ((float4*)Af)[t] = Af_g[t];
        ((float4*)Ab)[t] = Ab_g[t];
    }
    __syncthreads();
    float acc[16];
    #pragma unroll
    for (int r=0;r<16;r++) acc[r]=0.f;
    const float4* Wsv = (const float4*)(Ws + j*64);
    const float4* Wdv = (const float4*)(Wd + j*64);
    for (int k4=0;k4<16;k4++){
        float4 a = Wsv[k4];
        float4 b = Wdv[k4];
        #pragma unroll
        for (int r=0;r<16;r++){
            float4 fa = Af[r][k4];
            float4 fb = Ab[r][k4];
            acc[r] += a.x*fa.x + a.y*fa.y + a.z*fa.z + a.w*fa.w
                    + b.x*fb.x + b.y*fb.y + b.z*fb.z + b.w*fb.w;
        }
    }
    float bias = 0.5f*(bs[j] + bd[j]);
    #pragma unroll
    for (int r=0;r<16;r++) out[(size_t)(row0+r)*128 + j] = __float2bfloat16(0.5f*acc[r] + bias);
}

// ---------------- MFMA gates GEMM: gates[64000][512] = X2 @ Wc^T + biasc ----------------
__global__ __launch_bounds__(256) void gemmg(
        const unsigned short* __restrict__ X2, const unsigned short* __restrict__ wpc,
        const float* __restrict__ biasc, unsigned short* __restrict__ gates, int gn_base){
    __shared__ unsigned short As[2][64*40];
    int tid  = threadIdx.x;
    int wave = tid >> 6, lane = tid & 63;
    int quad = lane >> 4, l16 = lane & 15;
    int nb = blockIdx.x & 7, mb = blockIdx.x >> 3;
    int m0 = mb*64;
    int col = nb*64 + wave*16 + l16;
    bf16x8 bq[8];
    #pragma unroll
    for (int ks=0; ks<8; ks++)
        bq[ks] = *(const bf16x8*)(wpc + (size_t)col*256 + ks*32 + quad*8);
    f32x4 acc[4];
    #pragma unroll
    for (int t=0;t<4;t++) acc[t] = (f32x4){0.f,0.f,0.f,0.f};
    int srow = tid>>2, sch = tid&3;
    const unsigned short* src_base = X2 + (size_t)(gn_base + m0 + srow)*256 + sch*8;
    *(float4*)(&As[0][srow*40 + sch*8]) = *(const float4*)(src_base);
    __syncthreads();
    for (int ks=0; ks<8; ks++){
        if (ks < 7)
            *(float4*)(&As[(ks+1)&1][srow*40 + sch*8]) = *(const float4*)(src_base + (ks+1)*32);
        const unsigned short* ab = As[ks&1];
        #pragma unroll
        for (int t=0;t<4;t++){
            bf16x8 a = *(const bf16x8*)(ab + (t*16 + l16)*40 + quad*8);
            acc[t] = __builtin_amdgcn_mfma_f32_16x16x32_bf16(a, bq[ks], acc[t], 0, 0, 0);
        }
        __syncthreads();
    }
    float bc = biasc[col];
    #pragma unroll
    for (int t=0;t<4;t++){
        #pragma unroll
        for (int r=0;r<4;r++){
            int grow = m0 + t*16 + quad*4 + r;
            gates[(size_t)grow*512 + col] = f2bfu(acc[t][r] + bc);
        }
    }
}

// ---------------- MFMA recurrent LSTM (8 steps) + projection ----------------
// 512 threads = 8 waves, 16 LSTM rows/block (one MFMA m-tile). Wave w owns
// hidden-unit stripe j in [w*16, w*16+16) for all 4 gates -> 4 col-tiles x 4
// K-tiles = 16 MFMA/step. Whh B-frags loaded ONCE into 64 VGPRs (step-invariant).
// h kept bf16 in LDS, stride 136 ushorts (2-way bank alias = free). c f32 in regs.
__global__ __launch_bounds__(512) void lstm7(
        const unsigned short* __restrict__ gates, long gn_base, int mbase,
        const unsigned short* __restrict__ whb,
        const float* __restrict__ wcv, const int* __restrict__ flag,
        void* __restrict__ out){
    __shared__ unsigned short hsh[16*136];
    int tid  = threadIdx.x;
    int w    = tid >> 6;
    int lane = tid & 63;
    int quad = lane >> 4, l15 = lane & 15;
    int m0   = mbase + blockIdx.x * 16;
    int isf32 = flag[0];

    // B-frags: bfrag[gate][ktile], lane holds Whh[col=gate*128+w*16+l15][k=kt*32+quad*8 ..+8]
    bf16x8 bfrag[4][4];
    #pragma unroll
    for (int g=0; g<4; g++)
        #pragma unroll
        for (int kt=0; kt<4; kt++)
            bfrag[g][kt] = *(const bf16x8*)(whb + (size_t)(g*128 + w*16 + l15)*128 + kt*32 + quad*8);

    for (int t=tid; t<16*136; t+=512) hsh[t] = 0;
    f32x4 c = (f32x4){0.f,0.f,0.f,0.f};
    __syncthreads();

    for (int step=0; step<8; step++){
        // init acc with x-gates (D-layout: row=quad*4+reg, col=lane&15)
        f32x4 acc[4];
        #pragma unroll
        for (int g=0; g<4; g++){
            #pragma unroll
            for (int r=0; r<4; r++){
                size_t gl = ((size_t)(m0 + quad*4 + r)*8 + step) - gn_base;
                acc[g][r] = bfu2f(gates[gl*512 + g*128 + w*16 + l15]);
            }
        }
        // h @ Whh^T via MFMA (A-frag shared by all waves)
        #pragma unroll
        for (int kt=0; kt<4; kt++){
            bf16x8 a = *(const bf16x8*)(hsh + l15*136 + kt*32 + quad*8);
            #pragma unroll
            for (int g=0; g<4; g++)
                acc[g] = __builtin_amdgcn_mfma_f32_16x16x32_bf16(a, bfrag[g][kt], acc[g], 0, 0, 0);
        }
        // nonlinearity: lane owns rows quad*4+{0..3}, hidden unit j=w*16+l15
        float hnew[4];
        #pragma unroll
        for (int r=0; r<4; r++){
            float gi = sigmf(acc[0][r]), gf = sigmf(acc[1][r]);
            float gg = tanhfast(acc[2][r]), go = sigmf(acc[3][r]);
            float cc = gf*c[r] + gi*gg;
            c[r] = cc;
            hnew[r] = go*tanhfast(cc);
        }
        __syncthreads();   // all waves done reading h of this step
        #pragma unroll
        for (int r=0; r<4; r++)
            hsh[(quad*4+r)*136 + w*16 + l15] = f2bfu(hnew[r]);
        __syncthreads();
    }
    // projection: out[m0+r][q] = h_last[r] . Wp[q] + bp[q]
    int r  = tid >> 5;
    int q0 = (tid & 31) * 2;
    float p0 = wcv[OFF_BP + q0], p1 = wcv[OFF_BP + q0 + 1];
    for (int k4=0;k4<32;k4++){
        float4 hv = cvtbf4(*(const ushort4*)(hsh + r*136 + k4*4));
        float4 w0 = *(const float4*)(wcv + OFF_WP + q0*128 + k4*4);
        float4 w1 = *(const float4*)(wcv + OFF_WP + (q0+1)*128 + k4*4);
        p0 += w0.x*hv.x + w0.y*hv.y + w0.z*hv.z + w0.w*hv.w;
        p1 += w1.x*hv.x + w1.y*hv.y + w1.z*hv.z + w1.w*hv.w;
    }
    long o = (long)(m0+r)*64 + q0;
    if (isf32){ ((float*)out)[o] = p0; ((float*)out)[o+1] = p1; }
    else { ((__hip_bfloat16*)out)[o] = __float2bfloat16(p0);
           ((__hip_bfloat16*)out)[o+1] = __float2bfloat16(p1); }
}

extern "C" void kernel_launch(void* const* d_in, const int* in_sizes, int n_in,
                              void* d_out, int out_size, void* d_ws, size_t ws_size,
                              hipStream_t stream){
    const void* x_seq      = d_in[0];
    const int*  edge_index = (const int*)d_in[1];
    const void* edge_weight= d_in[2];

    float* ws    = (float*)d_ws;
    int*   flag  = (int*)(ws + WS_FLAG);
    float* wcv   = ws + WS_WCV;
    unsigned short* whb = (unsigned short*)(ws + WS_WPH);
    unsigned short* wpc = (unsigned short*)(ws + WS_WPC);
    float* biasc = ws + WS_BIASC;
    float* deg_o = ws + WS_DEGO;
    float* deg_i = ws + WS_DEGI;
    int*   cnt_i = (int*)(ws + WS_CNTI);
    int*   cnt_o = (int*)(ws + WS_CNTO);
    int*   rp_i  = (int*)(ws + WS_RPI);
    int*   rp_o  = (int*)(ws + WS_RPO);
    int*   cur_i = (int*)(ws + WS_CURI);
    int*   cur_o = (int*)(ws + WS_CURO);
    int2*  csr_i = (int2*)(ws + WS_CSRI);
    int2*  csr_o = (int2*)(ws + WS_CSRO);
    unsigned short* X2 = (unsigned short*)(ws + WS_X2);
    unsigned short* Xb = X2;             // aliases X2 (dead once gather128 writes X2)
    __hip_bfloat16* Hb = (__hip_bfloat16*)(ws + WS_HB);
    unsigned short* GT = (unsigned short*)(ws + WS_GT);
    float* P0 = ws + WS_GT;              // aliases GT (dead before gates written)
    float* Q0 = P0 + (size_t)GN_*64;

    sniff_kernel<<<1, 256, 0, stream>>>((const unsigned int*)edge_weight, flag);
    WDesc wd;
    wd.seg[0]  = { d_in[3],  OFF_W0S, 8192  };
    wd.seg[1]  = { d_in[4],  OFF_B0S, 128   };
    wd.seg[2]  = { d_in[5],  OFF_W0D, 8192  };
    wd.seg[3]  = { d_in[6],  OFF_B0D, 128   };
    wd.seg[4]  = { d_in[7],  OFF_W1S, 16384 };
    wd.seg[5]  = { d_in[8],  OFF_B1S, 128   };
    wd.seg[6]  = { d_in[9],  OFF_W1D, 16384 };
    wd.seg[7]  = { d_in[10], OFF_B1D, 128   };
    wd.seg[8]  = { d_in[11], OFF_WIH, 65536 };
    wd.seg[9]  = { d_in[12], OFF_WHH, 65536 };
    wd.seg[10] = { d_in[13], OFF_BIH, 512   };
    wd.seg[11] = { d_in[14], OFF_BHH, 512   };
    wd.seg[12] = { d_in[15], OFF_WP,  8192  };
    wd.seg[13] = { d_in[16], OFF_BP,  64    };
    convert_weights<<<(WCV_TOTAL+255)/256, 256, 0, stream>>>(wd, wcv, flag);
    repack_whh<<<256, 256, 0, stream>>>(wcv, whb);
    compose_wc<<<512, 256, 0, stream>>>(wcv, wpc);
    compose_bias<<<2, 256, 0, stream>>>(wcv, biasc);
    xcvt_kernel<<<(GN_*64+255)/256, 256, 0, stream>>>(x_seq, flag, Xb);

    hist_kernel<<<G_, 1024, 0, stream>>>(edge_index, edge_weight, flag, deg_o, deg_i, cnt_i, cnt_o);
    scan_kernel<<<64, 256, 0, stream>>>(cnt_i, cnt_o, rp_i, rp_o, cur_i, cur_o);
    fill_kernel<<<(GE_+255)/256, 256, 0, stream>>>(edge_index, edge_weight, flag,
                                                   deg_o, deg_i, cur_i, cur_o, csr_i, csr_o);

    // layer 0: gather (bf16 Xb) -> P0,Q0 ; GEMM -> Hb (bf16)
    gather64<<<2*G_*N_/4, 256, 0, stream>>>(rp_i, rp_o, csr_i, csr_o, Xb, P0, Q0);
    gemm_dir64<<<GN_/16, 128, 0, stream>>>(P0, Q0,
        wcv+OFF_W0S, wcv+OFF_B0S, wcv+OFF_W0D, wcv+OFF_B0D, Hb);

    // layer 1: gather -> X2 (bf16, overwrites Xb); per-half: MFMA gates + MFMA LSTM
    gather128<<<2*G_*N_/4, 256, 0, stream>>>(rp_i, rp_o, csr_i, csr_o, Hb, X2);

    gemmg<<<8*(HALF_GN/64), 256, 0, stream>>>(X2, wpc, biasc, GT, 0);
    lstm7<<<HALF_M/16, 512, 0, stream>>>(GT, 0L, 0, whb, wcv, flag, d_out);

    gemmg<<<8*(HALF_GN/64), 256, 0, stream>>>(X2, wpc, biasc, GT, HALF_GN);
    lstm7<<<HALF_M/16, 512, 0, stream>>>(GT, (long)HALF_GN, HALF_M, whb, wcv, flag, d_out);
}

// Round 9
// 914.294 us; speedup vs baseline: 1.9877x; 1.1328x over previous
//
#include <hip/hip_runtime.h>
#include <hip/hip_bf16.h>

// Problem constants (B,S,N,F,H,E) = (4,8,4000,64,128,32000)
#define B_  4
#define S_  8
#define N_  4000
#define F_  64
#define H_  128
#define E_  32000
#define G_  (B_*S_)        // 32 graphs
#define GN_ (G_*N_)        // 128000 node rows
#define M_  (B_*N_)        // 16000 LSTM rows
#define GE_ (G_*E_)        // 1,024,000 edges total
#define HALF_GN 64000
#define HALF_M  8000

// f32 weight scratch offsets (floats)
#define OFF_W0S 0
#define OFF_B0S 8192
#define OFF_W0D 8320
#define OFF_B0D 16512
#define OFF_W1S 16640
#define OFF_B1S 33024
#define OFF_W1D 33152
#define OFF_B1D 49536
#define OFF_WIH 49664
#define OFF_WHH 115200
#define OFF_BIH 180736
#define OFF_BHH 181248
#define OFF_WP  181760
#define OFF_BP  189952
#define WCV_TOTAL 190016

// workspace layout (float offsets)
#define WS_FLAG   0
#define WS_WCV    16
#define WS_WPH    190032      // Whh bf16 [512][128]: 65536 ushorts
#define WS_WPC    222800      // composed Wc bf16 [512][256]: 131072 ushorts
#define WS_BIASC  288336      // 512 f32
#define WS_DEGO   288848
#define WS_DEGI   416848
#define WS_CNTI   544848
#define WS_CNTO   672848
#define WS_RPI    800848      // 32*4001
#define WS_RPO    928880
#define WS_CURI   1056912
#define WS_CURO   1184912
#define WS_CSRI   1312912     // int2 x GE
#define WS_CSRO   3360912
#define WS_X2     5408912     // [GN][256] bf16; first 8.2M ushorts alias Xb [GN][64] bf16
#define WS_HB     21792912    // [GN][128] bf16
#define WS_GT     29984912    // gates half [64000][512] bf16; aliases PQ0 bf16 [GN][128]
#define WS_WC0    46368912    // Wc0 bf16 [128][128]: 16384 ushorts = 8192 floats
// end: 46,377,104 floats = 185.5 MiB (proven budget >= 193 MiB)

typedef __attribute__((ext_vector_type(8))) short bf16x8;
typedef __attribute__((ext_vector_type(4))) float f32x4;

__device__ inline float bfu2f(unsigned short u){ union{unsigned int i; float f;} v; v.i=((unsigned int)u)<<16; return v.f; }
__device__ inline unsigned short f2bfu(float f){ __hip_bfloat16 b = __float2bfloat16(f); return *(unsigned short*)&b; }
__device__ inline float rcpf(float x){ return __builtin_amdgcn_rcpf(x); }
__device__ inline float sigmf(float x){ return rcpf(1.0f + __expf(-x)); }
__device__ inline float tanhfast(float x){ return 1.0f - 2.0f*rcpf(1.0f + __expf(2.0f*x)); }
__device__ inline float loadf(const void* p, long i, int isf32){
    return isf32 ? ((const float*)p)[i]
                 : __bfloat162float(((const __hip_bfloat16*)p)[i]);
}
__device__ inline float4 cvtbf4(ushort4 u){
    float4 f;
    f.x = __uint_as_float(((unsigned)u.x)<<16);
    f.y = __uint_as_float(((unsigned)u.y)<<16);
    f.z = __uint_as_float(((unsigned)u.z)<<16);
    f.w = __uint_as_float(((unsigned)u.w)<<16);
    return f;
}

// ---------------- dtype sniff (inputs f32 vs bf16) ----------------
__global__ void sniff_kernel(const unsigned int* __restrict__ ew, int* __restrict__ flag){
    __shared__ int s;
    if (threadIdx.x == 0) s = 0;
    __syncthreads();
    unsigned int lo = ew[threadIdx.x] & 0xFFFFu;
    if (lo > 0x3F80u) atomicOr(&s, 1);
    __syncthreads();
    if (threadIdx.x == 0) flag[0] = s;   // 1 => inputs are f32
}

// ---------------- weight conversion to f32 scratch ----------------
struct WSeg { const void* src; int base; int n; };
struct WDesc { WSeg seg[14]; };
__global__ void convert_weights(WDesc d, float* __restrict__ dst, const int* __restrict__ flag){
    int isf32 = flag[0];
    int idx = blockIdx.x*256 + threadIdx.x;
    #pragma unroll
    for (int s=0;s<14;s++){
        int off = idx - d.seg[s].base;
        if (off >= 0 && off < d.seg[s].n){
            dst[idx] = loadf(d.seg[s].src, off, isf32);
            return;
        }
    }
}

// ---------------- Whh bf16 copy ----------------
__global__ void repack_whh(const float* __restrict__ wcv, unsigned short* __restrict__ whb){
    int idx = blockIdx.x*256 + threadIdx.x;   // < 65536
    whb[idx] = f2bfu(wcv[OFF_WHH + idx]);
}

// ---------------- layer-0 composed weights: Wc0[n][k] bf16 [128][128] ----------------
// k<64: 0.5*W0s[n][k] ; k>=64: 0.5*W0d[n][k-64]
__global__ void repack_wc0(const float* __restrict__ wcv, unsigned short* __restrict__ wc0){
    int idx = blockIdx.x*256 + threadIdx.x;   // < 16384
    int k = idx & 127, n = idx >> 7;
    float v = (k < 64) ? 0.5f*wcv[OFF_W0S + n*64 + k] : 0.5f*wcv[OFF_W0D + n*64 + (k-64)];
    wc0[idx] = f2bfu(v);
}

// ---------------- x_seq -> bf16 Xb [GN][64] ----------------
__global__ void xcvt_kernel(const void* __restrict__ x, const int* __restrict__ flag,
                            unsigned short* __restrict__ Xb){
    long idx = (long)blockIdx.x*256 + threadIdx.x;
    if (idx >= (long)GN_*64) return;
    Xb[idx] = f2bfu(loadf(x, idx, flag[0]));
}

// ---------------- composed weights: Wc[n][k] bf16 [512][256] ----------------
__global__ __launch_bounds__(256) void compose_wc(const float* __restrict__ wcv,
                                                  unsigned short* __restrict__ wpc){
    int n = blockIdx.x;        // 512 blocks
    int k = threadIdx.x;       // 256
    const float* wih = wcv + OFF_WIH + n*128;
    const float* w1  = (k < 128) ? (wcv + OFF_W1S + k) : (wcv + OFF_W1D + (k-128));
    float s = 0.f;
    for (int h=0; h<128; h++) s += wih[h] * w1[h*128];
    wpc[n*256 + k] = f2bfu(0.5f * s);
}

// biasc[n] = bih[n]+bhh[n] + sum_h Wih[n][h]*0.5*(b1s[h]+b1d[h])
__global__ void compose_bias(const float* __restrict__ wcv, float* __restrict__ biasc){
    int n = blockIdx.x*256 + threadIdx.x;
    if (n >= 512) return;
    float s = wcv[OFF_BIH+n] + wcv[OFF_BHH+n];
    const float* wih = wcv + OFF_WIH + n*128;
    for (int h=0; h<128; h++) s += wih[h] * 0.5f*(wcv[OFF_B1S+h] + wcv[OFF_B1D+h]);
    biasc[n] = s;
}

// ---------------- per-graph histogram: weighted degrees + counts ----------------
__global__ __launch_bounds__(1024) void hist_kernel(
        const int* __restrict__ ei, const void* __restrict__ ew, const int* __restrict__ flag,
        float* __restrict__ deg_o, float* __restrict__ deg_i,
        int* __restrict__ cnt_in, int* __restrict__ cnt_out){
    __shared__ float wdo[N_], wdi[N_];
    __shared__ int   co[N_],  ci[N_];
    int g = blockIdx.x, tid = threadIdx.x;
    int isf32 = flag[0];
    for (int i=tid;i<N_;i+=1024){ wdo[i]=0.f; wdi[i]=0.f; co[i]=0; ci[i]=0; }
    __syncthreads();
    const int* eib = ei + g*2*E_;
    for (int e=tid;e<E_;e+=1024){
        int s = eib[e], d = eib[E_+e];
        float w = loadf(ew, (long)g*E_+e, isf32);
        atomicAdd(&wdo[s], w); atomicAdd(&wdi[d], w);
        atomicAdd(&co[s], 1);  atomicAdd(&ci[d], 1);
    }
    __syncthreads();
    for (int i=tid;i<N_;i+=1024){
        deg_o[g*N_+i]=wdo[i]; deg_i[g*N_+i]=wdi[i];
        cnt_out[g*N_+i]=co[i]; cnt_in[g*N_+i]=ci[i];
    }
}

// ---------------- exclusive scan -> row_ptr + cursors ----------------
__global__ __launch_bounds__(256) void scan_kernel(
        const int* __restrict__ cnt_in, const int* __restrict__ cnt_out,
        int* __restrict__ rp_in, int* __restrict__ rp_out,
        int* __restrict__ cur_in, int* __restrict__ cur_out){
    __shared__ int part[256], pref[256];
    int g = blockIdx.x & 31, dir = blockIdx.x >> 5;
    const int* cnt = (dir ? cnt_out : cnt_in) + g*N_;
    int* rp  = (dir ? rp_out  : rp_in)  + g*(N_+1);
    int* cur = (dir ? cur_out : cur_in) + g*N_;
    int tid = threadIdx.x, base = tid*16;
    int sum = 0;
    for (int i=0;i<16;i++){ int p = base+i; if (p < N_) sum += cnt[p]; }
    part[tid] = sum;
    __syncthreads();
    if (tid == 0){ int run = 0; for (int j=0;j<256;j++){ pref[j] = run; run += part[j]; } }
    __syncthreads();
    int run = pref[tid];
    for (int i=0;i<16;i++){
        int p = base+i;
        if (p < N_){ rp[p] = run; cur[p] = run; run += cnt[p]; }
    }
    if (tid == 255) rp[N_] = run;
}

// ---------------- fill CSR ----------------
__global__ void fill_kernel(const int* __restrict__ ei, const void* __restrict__ ew,
                            const int* __restrict__ flag,
                            const float* __restrict__ deg_o, const float* __restrict__ deg_i,
                            int* __restrict__ cur_in, int* __restrict__ cur_out,
                            int2* __restrict__ csr_in, int2* __restrict__ csr_out){
    int idx = blockIdx.x*256 + threadIdx.x;
    if (idx >= GE_) return;
    int isf32 = flag[0];
    int g = idx / E_, e = idx - g*E_;
    const int* eib = ei + g*2*E_;
    int s = eib[e], d = eib[E_ + e];
    float dout = deg_o[g*N_+s], din = deg_i[g*N_+d];
    float io = dout > 0.f ? rsqrtf(fmaxf(dout, 1e-12f)) : 0.f;
    float ii = din  > 0.f ? rsqrtf(fmaxf(din , 1e-12f)) : 0.f;
    float nrm = loadf(ew, idx, isf32) * io * ii;
    int p1 = atomicAdd(&cur_in[g*N_+d], 1);
    csr_in[(long)g*E_ + p1] = make_int2(s, __float_as_int(nrm));
    int p2 = atomicAdd(&cur_out[g*N_+s], 1);
    csr_out[(long)g*E_ + p2] = make_int2(d, __float_as_int(nrm));
}

// ---------------- gather layer 0 -> PQ0 bf16 [GN][128] (dir0 cols 0..63, dir1 64..127) ----------------
// XCD swizzle: blockIdx&7 -> xcd -> graphs xcd*4..+4 so each XCD's L2 holds only
// 4 graphs' Xb slice (2 MB). Dispatch round-robin assumption: perf-only.
__global__ void gather64(const int* __restrict__ rp_in, const int* __restrict__ rp_out,
                         const int2* __restrict__ csr_in, const int2* __restrict__ csr_out,
                         const unsigned short* __restrict__ Xb,
                         unsigned short* __restrict__ PQ0){
    int xcd  = blockIdx.x & 7;
    int rest = blockIdx.x >> 3;            // 0..7999
    int g    = xcd*4 + (rest & 3);
    int wl   = (rest >> 2)*4 + (threadIdx.x>>6);   // 0..7999 = 2N
    int lane = threadIdx.x & 63;
    int dir = wl / N_;   int n = wl - dir*N_;
    const int*  rp  = (dir ? rp_out : rp_in) + g*(N_+1);
    const int2* csr = (dir ? csr_out : csr_in) + (long)g*E_;
    int pb = rp[n], pe = rp[n+1];
    float acc = 0.f;
    for (int p=pb; p<pe; p++){
        int2 ent = csr[p];
        float w = __int_as_float(ent.y);
        acc += w * bfu2f(Xb[((long)(g*N_+ent.x))*64 + lane]);
    }
    PQ0[((long)(g*N_+n))*128 + dir*64 + lane] = f2bfu(acc);
}

// ---------------- gather layer 1 -> X2 bf16 [GN][256] (XCD-swizzled) ----------------
__global__ void gather128(const int* __restrict__ rp_in, const int* __restrict__ rp_out,
                          const int2* __restrict__ csr_in, const int2* __restrict__ csr_out,
                          const __hip_bfloat16* __restrict__ hb,
                          unsigned short* __restrict__ X2){
    int xcd  = blockIdx.x & 7;
    int rest = blockIdx.x >> 3;
    int g    = xcd*4 + (rest & 3);
    int wl   = (rest >> 2)*4 + (threadIdx.x>>6);
    int lane = threadIdx.x & 63;
    int dir = wl / N_;   int n = wl - dir*N_;
    const int*  rp  = (dir ? rp_out : rp_in) + g*(N_+1);
    const int2* csr = (dir ? csr_out : csr_in) + (long)g*E_;
    int pb = rp[n], pe = rp[n+1];
    float2 acc = make_float2(0.f, 0.f);
    for (int p=pb; p<pe; p++){
        int2 ent = csr[p];
        float w = __int_as_float(ent.y);
        ushort2 u = ((const ushort2*)(hb + ((long)(g*N_+ent.x))*128))[lane];
        acc.x += w*bfu2f(u.x); acc.y += w*bfu2f(u.y);
    }
    ushort2 o; o.x = f2bfu(acc.x); o.y = f2bfu(acc.y);
    ((ushort2*)(X2 + (size_t)(g*N_+n)*256 + dir*128))[lane] = o;
}

// ---------------- MFMA layer-0 GEMM: Hb[GN][128] = PQ0 @ Wc0^T + 0.5(b0s+b0d) ----------------
// same tile structure as gemmg, K=128 (4 ks-chunks), 2 col-tiles of 64.
__global__ __launch_bounds__(256) void gemm0(
        const unsigned short* __restrict__ PQ0, const unsigned short* __restrict__ wc0,
        const float* __restrict__ wcv, __hip_bfloat16* __restrict__ Hb){
    __shared__ unsigned short As[2][64*40];
    int tid  = threadIdx.x;
    int wave = tid >> 6, lane = tid & 63;
    int quad = lane >> 4, l16 = lane & 15;
    int nb = blockIdx.x & 1, mb = blockIdx.x >> 1;
    int m0 = mb*64;
    int col = nb*64 + wave*16 + l16;
    bf16x8 bq[4];
    #pragma unroll
    for (int ks=0; ks<4; ks++)
        bq[ks] = *(const bf16x8*)(wc0 + (size_t)col*128 + ks*32 + quad*8);
    f32x4 acc[4];
    #pragma unroll
    for (int t=0;t<4;t++) acc[t] = (f32x4){0.f,0.f,0.f,0.f};
    int srow = tid>>2, sch = tid&3;
    const unsigned short* src_base = PQ0 + (size_t)(m0 + srow)*128 + sch*8;
    *(float4*)(&As[0][srow*40 + sch*8]) = *(const float4*)(src_base);
    __syncthreads();
    for (int ks=0; ks<4; ks++){
        if (ks < 3)
            *(float4*)(&As[(ks+1)&1][srow*40 + sch*8]) = *(const float4*)(src_base + (ks+1)*32);
        const unsigned short* ab = As[ks&1];
        #pragma unroll
        for (int t=0;t<4;t++){
            bf16x8 a = *(const bf16x8*)(ab + (t*16 + l16)*40 + quad*8);
            acc[t] = __builtin_amdgcn_mfma_f32_16x16x32_bf16(a, bq[ks], acc[t], 0, 0, 0);
        }
        __syncthreads();
    }
    float bias = 0.5f*(wcv[OFF_B0S+col] + wcv[OFF_B0D+col]);
    #pragma unroll
    for (int t=0;t<4;t++){
        #pragma unroll
        for (int r=0;r<4;r++){
            int grow = m0 + t*16 + quad*4 + r;
            Hb[(size_t)grow*128 + col] = __float2bfloat16(acc[t][r] + bias);
        }
    }
}

// ---------------- MFMA gates GEMM: gates[64000][512] = X2 @ Wc^T + biasc ----------------
__global__ __launch_bounds__(256) void gemmg(
        const unsigned short* __restrict__ X2, const unsigned short* __restrict__ wpc,
        const float* __restrict__ biasc, unsigned short* __restrict__ gates, int gn_base){
    __shared__ unsigned short As[2][64*40];
    int tid  = threadIdx.x;
    int wave = tid >> 6, lane = tid & 63;
    int quad = lane >> 4, l16 = lane & 15;
    int nb = blockIdx.x & 7, mb = blockIdx.x >> 3;
    int m0 = mb*64;
    int col = nb*64 + wave*16 + l16;
    bf16x8 bq[8];
    #pragma unroll
    for (int ks=0; ks<8; ks++)
        bq[ks] = *(const bf16x8*)(wpc + (size_t)col*256 + ks*32 + quad*8);
    f32x4 acc[4];
    #pragma unroll
    for (int t=0;t<4;t++) acc[t] = (f32x4){0.f,0.f,0.f,0.f};
    int srow = tid>>2, sch = tid&3;
    const unsigned short* src_base = X2 + (size_t)(gn_base + m0 + srow)*256 + sch*8;
    *(float4*)(&As[0][srow*40 + sch*8]) = *(const float4*)(src_base);
    __syncthreads();
    for (int ks=0; ks<8; ks++){
        if (ks < 7)
            *(float4*)(&As[(ks+1)&1][srow*40 + sch*8]) = *(const float4*)(src_base + (ks+1)*32);
        const unsigned short* ab = As[ks&1];
        #pragma unroll
        for (int t=0;t<4;t++){
            bf16x8 a = *(const bf16x8*)(ab + (t*16 + l16)*40 + quad*8);
            acc[t] = __builtin_amdgcn_mfma_f32_16x16x32_bf16(a, bq[ks], acc[t], 0, 0, 0);
        }
        __syncthreads();
    }
    float bc = biasc[col];
    #pragma unroll
    for (int t=0;t<4;t++){
        #pragma unroll
        for (int r=0;r<4;r++){
            int grow = m0 + t*16 + quad*4 + r;
            gates[(size_t)grow*512 + col] = f2bfu(acc[t][r] + bc);
        }
    }
}

// ---------------- MFMA recurrent LSTM (8 steps) + projection ----------------
__global__ __launch_bounds__(512) void lstm7(
        const unsigned short* __restrict__ gates, long gn_base, int mbase,
        const unsigned short* __restrict__ whb,
        const float* __restrict__ wcv, const int* __restrict__ flag,
        void* __restrict__ out){
    __shared__ unsigned short hsh[16*136];
    int tid  = threadIdx.x;
    int w    = tid >> 6;
    int lane = tid & 63;
    int quad = lane >> 4, l15 = lane & 15;
    int m0   = mbase + blockIdx.x * 16;
    int isf32 = flag[0];

    bf16x8 bfrag[4][4];
    #pragma unroll
    for (int g=0; g<4; g++)
        #pragma unroll
        for (int kt=0; kt<4; kt++)
            bfrag[g][kt] = *(const bf16x8*)(whb + (size_t)(g*128 + w*16 + l15)*128 + kt*32 + quad*8);

    for (int t=tid; t<16*136; t+=512) hsh[t] = 0;
    f32x4 c = (f32x4){0.f,0.f,0.f,0.f};
    __syncthreads();

    for (int step=0; step<8; step++){
        f32x4 acc[4];
        #pragma unroll
        for (int g=0; g<4; g++){
            #pragma unroll
            for (int r=0; r<4; r++){
                size_t gl = ((size_t)(m0 + quad*4 + r)*8 + step) - gn_base;
                acc[g][r] = bfu2f(gates[gl*512 + g*128 + w*16 + l15]);
            }
        }
        #pragma unroll
        for (int kt=0; kt<4; kt++){
            bf16x8 a = *(const bf16x8*)(hsh + l15*136 + kt*32 + quad*8);
            #pragma unroll
            for (int g=0; g<4; g++)
                acc[g] = __builtin_amdgcn_mfma_f32_16x16x32_bf16(a, bfrag[g][kt], acc[g], 0, 0, 0);
        }
        float hnew[4];
        #pragma unroll
        for (int r=0; r<4; r++){
            float gi = sigmf(acc[0][r]), gf = sigmf(acc[1][r]);
            float gg = tanhfast(acc[2][r]), go = sigmf(acc[3][r]);
            float cc = gf*c[r] + gi*gg;
            c[r] = cc;
            hnew[r] = go*tanhfast(cc);
        }
        __syncthreads();
        #pragma unroll
        for (int r=0; r<4; r++)
            hsh[(quad*4+r)*136 + w*16 + l15] = f2bfu(hnew[r]);
        __syncthreads();
    }
    int r  = tid >> 5;
    int q0 = (tid & 31) * 2;
    float p0 = wcv[OFF_BP + q0], p1 = wcv[OFF_BP + q0 + 1];
    for (int k4=0;k4<32;k4++){
        float4 hv = cvtbf4(*(const ushort4*)(hsh + r*136 + k4*4));
        float4 w0 = *(const float4*)(wcv + OFF_WP + q0*128 + k4*4);
        float4 w1 = *(const float4*)(wcv + OFF_WP + (q0+1)*128 + k4*4);
        p0 += w0.x*hv.x + w0.y*hv.y + w0.z*hv.z + w0.w*hv.w;
        p1 += w1.x*hv.x + w1.y*hv.y + w1.z*hv.z + w1.w*hv.w;
    }
    long o = (long)(m0+r)*64 + q0;
    if (isf32){ ((float*)out)[o] = p0; ((float*)out)[o+1] = p1; }
    else { ((__hip_bfloat16*)out)[o] = __float2bfloat16(p0);
           ((__hip_bfloat16*)out)[o+1] = __float2bfloat16(p1); }
}

extern "C" void kernel_launch(void* const* d_in, const int* in_sizes, int n_in,
                              void* d_out, int out_size, void* d_ws, size_t ws_size,
                              hipStream_t stream){
    const void* x_seq      = d_in[0];
    const int*  edge_index = (const int*)d_in[1];
    const void* edge_weight= d_in[2];

    float* ws    = (float*)d_ws;
    int*   flag  = (int*)(ws + WS_FLAG);
    float* wcv   = ws + WS_WCV;
    unsigned short* whb = (unsigned short*)(ws + WS_WPH);
    unsigned short* wpc = (unsigned short*)(ws + WS_WPC);
    unsigned short* wc0 = (unsigned short*)(ws + WS_WC0);
    float* biasc = ws + WS_BIASC;
    float* deg_o = ws + WS_DEGO;
    float* deg_i = ws + WS_DEGI;
    int*   cnt_i = (int*)(ws + WS_CNTI);
    int*   cnt_o = (int*)(ws + WS_CNTO);
    int*   rp_i  = (int*)(ws + WS_RPI);
    int*   rp_o  = (int*)(ws + WS_RPO);
    int*   cur_i = (int*)(ws + WS_CURI);
    int*   cur_o = (int*)(ws + WS_CURO);
    int2*  csr_i = (int2*)(ws + WS_CSRI);
    int2*  csr_o = (int2*)(ws + WS_CSRO);
    unsigned short* X2 = (unsigned short*)(ws + WS_X2);
    unsigned short* Xb = X2;             // aliases X2 (dead once gather128 writes X2)
    __hip_bfloat16* Hb = (__hip_bfloat16*)(ws + WS_HB);
    unsigned short* GT = (unsigned short*)(ws + WS_GT);
    unsigned short* PQ0 = GT;            // aliases GT (dead before gates written)

    sniff_kernel<<<1, 256, 0, stream>>>((const unsigned int*)edge_weight, flag);
    WDesc wd;
    wd.seg[0]  = { d_in[3],  OFF_W0S, 8192  };
    wd.seg[1]  = { d_in[4],  OFF_B0S, 128   };
    wd.seg[2]  = { d_in[5],  OFF_W0D, 8192  };
    wd.seg[3]  = { d_in[6],  OFF_B0D, 128   };
    wd.seg[4]  = { d_in[7],  OFF_W1S, 16384 };
    wd.seg[5]  = { d_in[8],  OFF_B1S, 128   };
    wd.seg[6]  = { d_in[9],  OFF_W1D, 16384 };
    wd.seg[7]  = { d_in[10], OFF_B1D, 128   };
    wd.seg[8]  = { d_in[11], OFF_WIH, 65536 };
    wd.seg[9]  = { d_in[12], OFF_WHH, 65536 };
    wd.seg[10] = { d_in[13], OFF_BIH, 512   };
    wd.seg[11] = { d_in[14], OFF_BHH, 512   };
    wd.seg[12] = { d_in[15], OFF_WP,  8192  };
    wd.seg[13] = { d_in[16], OFF_BP,  64    };
    convert_weights<<<(WCV_TOTAL+255)/256, 256, 0, stream>>>(wd, wcv, flag);
    repack_whh<<<256, 256, 0, stream>>>(wcv, whb);
    repack_wc0<<<64, 256, 0, stream>>>(wcv, wc0);
    compose_wc<<<512, 256, 0, stream>>>(wcv, wpc);
    compose_bias<<<2, 256, 0, stream>>>(wcv, biasc);
    xcvt_kernel<<<(GN_*64+255)/256, 256, 0, stream>>>(x_seq, flag, Xb);

    hist_kernel<<<G_, 1024, 0, stream>>>(edge_index, edge_weight, flag, deg_o, deg_i, cnt_i, cnt_o);
    scan_kernel<<<64, 256, 0, stream>>>(cnt_i, cnt_o, rp_i, rp_o, cur_i, cur_o);
    fill_kernel<<<(GE_+255)/256, 256, 0, stream>>>(edge_index, edge_weight, flag,
                                                   deg_o, deg_i, cur_i, cur_o, csr_i, csr_o);

    // layer 0: gather (bf16 Xb, XCD-swizzled) -> PQ0 bf16 ; MFMA GEMM -> Hb (bf16)
    gather64<<<2*G_*N_/4, 256, 0, stream>>>(rp_i, rp_o, csr_i, csr_o, Xb, PQ0);
    gemm0<<<2*(GN_/64), 256, 0, stream>>>(PQ0, wc0, wcv, Hb);

    // layer 1: gather (XCD-swizzled) -> X2 (overwrites Xb); per-half: MFMA gates + MFMA LSTM
    gather128<<<2*G_*N_/4, 256, 0, stream>>>(rp_i, rp_o, csr_i, csr_o, Hb, X2);

    gemmg<<<8*(HALF_GN/64), 256, 0, stream>>>(X2, wpc, biasc, GT, 0);
    lstm7<<<HALF_M/16, 512, 0, stream>>>(GT, 0L, 0, whb, wcv, flag, d_out);

    gemmg<<<8*(HALF_GN/64), 256, 0, stream>>>(X2, wpc, biasc, GT, HALF_GN);
    lstm7<<<HALF_M/16, 512, 0, stream>>>(GT, (long)HALF_GN, HALF_M, whb, wcv, flag, d_out);
}